// Round 1
// baseline (89599.060 us; speedup 1.0000x reference)
//
#include <hip/hip_runtime.h>
#include <hip/hip_bf16.h>

#define DH 512
#define TT 1024
#define BB 64
#define DT 64

typedef _Float16 h2_t __attribute__((ext_vector_type(2)));

__device__ __forceinline__ float fdot2f(h2_t a, h2_t b, float c) {
#if __has_builtin(__builtin_amdgcn_fdot2)
  return __builtin_amdgcn_fdot2(a, b, c, false);
#else
  return c + (float)a[0] * (float)b[0] + (float)a[1] * (float)b[1];
#endif
}

// ET = (embedding @ w_x_0)^T, stored fp16 row-major in the transposed sense:
// ET[c*DH + r] = E'[r][c], so row c of ET is the c-th output column of E'.
__global__ __launch_bounds__(512) void eprime_kernel(
    const float* __restrict__ emb, const float* __restrict__ wx0,
    _Float16* __restrict__ ET)
{
  __shared__ float er[DH];
  const int r = blockIdx.x, c = threadIdx.x;
  er[c] = emb[(size_t)r * DH + c];
  __syncthreads();
  float acc = 0.f;
#pragma unroll 8
  for (int k = 0; k < DH; ++k) acc = fmaf(er[k], wx0[(size_t)k * DH + c], acc);
  ET[(size_t)c * DH + r] = (_Float16)acc;
}

// dst[j*DH + k] = (fp16) src[k*DH + j]   (weight transpose + fp16 cast)
__global__ __launch_bounds__(512) void transpose_half_kernel(
    const float* __restrict__ src, _Float16* __restrict__ dst)
{
  const int k = blockIdx.x, j = threadIdx.x;
  dst[(size_t)j * DH + k] = (_Float16)src[(size_t)k * DH + j];
}

__device__ __forceinline__ float dot512h(const _Float16* hv, const _Float16* wrow, float acc) {
  const h2_t* h2 = (const h2_t*)hv;
  const h2_t* w2 = (const h2_t*)wrow;
#pragma unroll 8
  for (int kk = 0; kk < DH / 2; ++kk) acc = fdot2f(h2[kk], w2[kk], acc);
  return acc;
}

// Combined mean/var over the 512 per-thread values v. Contains ONE __syncthreads.
__device__ __forceinline__ void block_stats(float v, float* red, int lane, int wave,
                                            float& mu, float& var) {
  float s = v, q = v * v;
#pragma unroll
  for (int off = 32; off > 0; off >>= 1) {
    s += __shfl_xor(s, off);
    q += __shfl_xor(q, off);
  }
  if (lane == 0) { red[wave] = s; red[8 + wave] = q; }
  __syncthreads();
  float ts = 0.f, tq = 0.f;
#pragma unroll
  for (int w = 0; w < 8; ++w) { ts += red[w]; tq += red[8 + w]; }
  mu = ts * (1.f / DH);
  var = tq * (1.f / DH) - mu * mu;
}

__global__ __launch_bounds__(512) void rnn_kernel(
    const float* __restrict__ inputs,
    const _Float16* __restrict__ ET,
    const _Float16* __restrict__ Wh0,
    const _Float16* __restrict__ Wx1,
    const _Float16* __restrict__ Wh1,
    const _Float16* __restrict__ Wx2,
    const _Float16* __restrict__ Wh2,
    const float* __restrict__ b0,
    const float* __restrict__ b1,
    const float* __restrict__ b2,
    const float* __restrict__ gamma,
    const float* __restrict__ beta,
    float* __restrict__ o2_out)
{
  const int b = blockIdx.x;
  const int j = threadIdx.x;
  const int lane = j & 63, wave = j >> 6;

  __shared__ _Float16 xh[DH];
  __shared__ _Float16 h0h[2][DH], h1h[2][DH], h2h[2][DH];
  __shared__ _Float16 o0h[DH], o1h[DH];
  __shared__ float red[16];

  const float bb0 = b0[j], bb1 = b1[j], bb2 = b2[j];
  const float gv = gamma[j], bev = beta[j];
  const float* xrow = inputs + (size_t)b * TT * DH;
  const _Float16* Ej   = ET  + (size_t)j * DH;
  const _Float16* Wh0j = Wh0 + (size_t)j * DH;
  const _Float16* Wx1j = Wx1 + (size_t)j * DH;
  const _Float16* Wh1j = Wh1 + (size_t)j * DH;
  const _Float16* Wx2j = Wx2 + (size_t)j * DH;
  const _Float16* Wh2j = Wh2 + (size_t)j * DH;

  h0h[0][j] = (_Float16)0.f;
  h1h[0][j] = (_Float16)0.f;
  h2h[0][j] = (_Float16)0.f;

  float mu, var;
  for (int t = 0; t < TT; ++t) {
    const int cur = t & 1, nxt = cur ^ 1;
    xh[j] = (_Float16)xrow[(size_t)t * DH + j];
    __syncthreads();                                     // B1: xh + prev h writes visible

    // layer 0: h0 = tanh(x @ E' + h0p @ Wh0 + b0)
    float a0 = bb0;
    a0 = dot512h(xh, Ej, a0);
    a0 = dot512h(h0h[cur], Wh0j, a0);
    const float v0 = tanhf(a0);
    h0h[nxt][j] = (_Float16)v0;
    block_stats(v0, red, lane, wave, mu, var);           // B2
    const float o0v = (v0 - mu) * rsqrtf(var + 1e-5f) * gv + bev;
    o0h[j] = (_Float16)o0v;
    __syncthreads();                                     // B3: o0 visible

    // layer 1
    float a1 = bb1;
    a1 = dot512h(o0h, Wx1j, a1);
    a1 = dot512h(h1h[cur], Wh1j, a1);
    const float v1 = tanhf(a1);
    h1h[nxt][j] = (_Float16)v1;
    block_stats(v1, red, lane, wave, mu, var);           // B4
    const float o1v = (v1 - mu) * rsqrtf(var + 1e-5f) * gv + bev;
    o1h[j] = (_Float16)o1v;
    __syncthreads();                                     // B5: o1 visible

    // layer 2
    float a2 = bb2;
    a2 = dot512h(o1h, Wx2j, a2);
    a2 = dot512h(h2h[cur], Wh2j, a2);
    const float v2 = tanhf(a2);
    h2h[nxt][j] = (_Float16)v2;

    if (t == TT - 1) {
      block_stats(v2, red, lane, wave, mu, var);         // B6 (uniform condition)
      o2_out[(size_t)b * DH + j] = (v2 - mu) * rsqrtf(var + 1e-5f) * gv + bev;
    }
  }
}

__global__ __launch_bounds__(64) void clf_kernel(
    const float* __restrict__ o2, const float* __restrict__ w,
    const float* __restrict__ bias, float* __restrict__ out)
{
  const int b = blockIdx.x, d = threadIdx.x;
  const float* ob = o2 + (size_t)b * DH;
  float acc = bias[d];
#pragma unroll 8
  for (int k = 0; k < DH; ++k) acc = fmaf(ob[k], w[(size_t)k * DT + d], acc);
  float m = acc;
#pragma unroll
  for (int off = 32; off > 0; off >>= 1) m = fmaxf(m, __shfl_xor(m, off));
  const float e = expf(acc - m);
  float s = e;
#pragma unroll
  for (int off = 32; off > 0; off >>= 1) s += __shfl_xor(s, off);
  out[(size_t)b * DT + d] = e / s;
}

extern "C" void kernel_launch(void* const* d_in, const int* in_sizes, int n_in,
                              void* d_out, int out_size, void* d_ws, size_t ws_size,
                              hipStream_t stream) {
  const float* inputs = (const float*)d_in[0];
  const float* emb    = (const float*)d_in[1];
  const float* wx0    = (const float*)d_in[2];
  const float* wh0    = (const float*)d_in[3];
  const float* b0     = (const float*)d_in[4];
  const float* wx1    = (const float*)d_in[5];
  const float* wh1    = (const float*)d_in[6];
  const float* b1     = (const float*)d_in[7];
  const float* wx2    = (const float*)d_in[8];
  const float* wh2    = (const float*)d_in[9];
  const float* b2     = (const float*)d_in[10];
  const float* gamma  = (const float*)d_in[11];
  const float* beta   = (const float*)d_in[12];
  const float* clfw   = (const float*)d_in[13];
  const float* clfb   = (const float*)d_in[14];
  float* out = (float*)d_out;

  char* ws = (char*)d_ws;
  const size_t MATB = (size_t)DH * DH * sizeof(_Float16);  // 512 KiB
  _Float16* ET   = (_Float16*)(ws + 0 * MATB);
  _Float16* WTh0 = (_Float16*)(ws + 1 * MATB);
  _Float16* WTx1 = (_Float16*)(ws + 2 * MATB);
  _Float16* WTh1 = (_Float16*)(ws + 3 * MATB);
  _Float16* WTx2 = (_Float16*)(ws + 4 * MATB);
  _Float16* WTh2 = (_Float16*)(ws + 5 * MATB);
  float*    o2   = (float*)(ws + 6 * MATB);                // 128 KiB

  hipLaunchKernelGGL(eprime_kernel, dim3(512), dim3(512), 0, stream, emb, wx0, ET);
  hipLaunchKernelGGL(transpose_half_kernel, dim3(512), dim3(512), 0, stream, wh0, WTh0);
  hipLaunchKernelGGL(transpose_half_kernel, dim3(512), dim3(512), 0, stream, wx1, WTx1);
  hipLaunchKernelGGL(transpose_half_kernel, dim3(512), dim3(512), 0, stream, wh1, WTh1);
  hipLaunchKernelGGL(transpose_half_kernel, dim3(512), dim3(512), 0, stream, wx2, WTx2);
  hipLaunchKernelGGL(transpose_half_kernel, dim3(512), dim3(512), 0, stream, wh2, WTh2);
  hipLaunchKernelGGL(rnn_kernel, dim3(BB), dim3(512), 0, stream,
                     inputs, ET, WTh0, WTx1, WTh1, WTx2, WTh2,
                     b0, b1, b2, gamma, beta, o2);
  hipLaunchKernelGGL(clf_kernel, dim3(BB), dim3(DT), 0, stream, o2, clfw, clfb, out);
}

// Round 2
// 23739.653 us; speedup vs baseline: 3.7742x; 3.7742x over previous
//
#include <hip/hip_runtime.h>

#define DH 512
#define TT 1024
#define BB 64
#define DT 64

typedef _Float16 h2_t __attribute__((ext_vector_type(2)));
typedef _Float16 h8_t __attribute__((ext_vector_type(8)));

__device__ __forceinline__ float fdot2f(h2_t a, h2_t b, float c) {
#if __has_builtin(__builtin_amdgcn_fdot2)
  return __builtin_amdgcn_fdot2(a, b, c, false);
#else
  return c + (float)a[0] * (float)b[0] + (float)a[1] * (float)b[1];
#endif
}

// E' = embedding @ w_x_0, written directly into packed-K layout:
// packed h8 element (k8*DH + c) holds E'[8k8+r][c] in half r.
__global__ __launch_bounds__(512) void eprime_kernel(
    const float* __restrict__ emb, const float* __restrict__ wx0,
    _Float16* __restrict__ Ep)
{
  __shared__ float er[DH];
  const int r = blockIdx.x, c = threadIdx.x;
  er[c] = emb[(size_t)r * DH + c];
  __syncthreads();
  float acc = 0.f;
#pragma unroll 8
  for (int k = 0; k < DH; ++k) acc = fmaf(er[k], wx0[(size_t)k * DH + c], acc);
  Ep[((size_t)(r >> 3) * DH + c) * 8 + (r & 7)] = (_Float16)acc;
}

// Pack 5 fp32 row-major [k][j] matrices into h8 K-major layout:
// dst h8 element (k8*DH + j) = rows 8k8..8k8+7 of column j.
__global__ __launch_bounds__(512) void pack_kernel(
    const float* __restrict__ s0, const float* __restrict__ s1,
    const float* __restrict__ s2, const float* __restrict__ s3,
    const float* __restrict__ s4, _Float16* __restrict__ d)
{
  const float* srcs[5] = {s0, s1, s2, s3, s4};
  const float* src = srcs[blockIdx.y];
  _Float16* dst = d + (size_t)blockIdx.y * DH * DH;
  const int k8 = blockIdx.x, j = threadIdx.x;
  h8_t v;
#pragma unroll
  for (int r = 0; r < 8; ++r) v[r] = (_Float16)src[(size_t)(8 * k8 + r) * DH + j];
  *(h8_t*)(dst + ((size_t)k8 * DH + j) * 8) = v;
}

// acc += sum_k W[k][j] * a[k], K-major packed weights, LDS-broadcast activations.
__device__ __forceinline__ float dot512(const h8_t* __restrict__ Wb,
                                        const _Float16* __restrict__ a,
                                        int j, float acc)
{
  const h8_t* av = (const h8_t*)a;
  float c0 = acc, c1 = 0.f, c2 = 0.f, c3 = 0.f;
#pragma unroll 8
  for (int k8 = 0; k8 < DH / 8; ++k8) {
    const h8_t w = Wb[(size_t)k8 * DH + j];
    const h8_t x = av[k8];
    c0 = fdot2f(__builtin_shufflevector(w, w, 0, 1), __builtin_shufflevector(x, x, 0, 1), c0);
    c1 = fdot2f(__builtin_shufflevector(w, w, 2, 3), __builtin_shufflevector(x, x, 2, 3), c1);
    c2 = fdot2f(__builtin_shufflevector(w, w, 4, 5), __builtin_shufflevector(x, x, 4, 5), c2);
    c3 = fdot2f(__builtin_shufflevector(w, w, 6, 7), __builtin_shufflevector(x, x, 6, 7), c3);
  }
  return (c0 + c1) + (c2 + c3);
}

// Combined mean/var over the 512 per-thread values v. Contains ONE __syncthreads.
__device__ __forceinline__ void block_stats(float v, float* red, int lane, int wave,
                                            float& mu, float& var) {
  float s = v, q = v * v;
#pragma unroll
  for (int off = 32; off > 0; off >>= 1) {
    s += __shfl_xor(s, off);
    q += __shfl_xor(q, off);
  }
  if (lane == 0) { red[wave] = s; red[8 + wave] = q; }
  __syncthreads();
  float ts = 0.f, tq = 0.f;
#pragma unroll
  for (int w = 0; w < 8; ++w) { ts += red[w]; tq += red[8 + w]; }
  mu = ts * (1.f / DH);
  var = tq * (1.f / DH) - mu * mu;
}

__global__ __launch_bounds__(512) void rnn_kernel(
    const float* __restrict__ inputs,
    const h8_t* __restrict__ Ep,
    const h8_t* __restrict__ Wh0,
    const h8_t* __restrict__ Wx1,
    const h8_t* __restrict__ Wh1,
    const h8_t* __restrict__ Wx2,
    const h8_t* __restrict__ Wh2,
    const float* __restrict__ b0,
    const float* __restrict__ b1,
    const float* __restrict__ b2,
    const float* __restrict__ gamma,
    const float* __restrict__ beta,
    float* __restrict__ o2_out)
{
  const int b = blockIdx.x;
  const int j = threadIdx.x;
  const int lane = j & 63, wave = j >> 6;

  __shared__ __align__(16) _Float16 xh[DH];
  __shared__ __align__(16) _Float16 h0h[2][DH], h1h[2][DH], h2h[2][DH];
  __shared__ __align__(16) _Float16 o0h[DH], o1h[DH];
  __shared__ float red[16];

  const float bb0 = b0[j], bb1 = b1[j], bb2 = b2[j];
  const float gv = gamma[j], bev = beta[j];
  const float* xrow = inputs + (size_t)b * TT * DH;

  h0h[0][j] = (_Float16)0.f;
  h1h[0][j] = (_Float16)0.f;
  h2h[0][j] = (_Float16)0.f;

  float mu, var;
  for (int t = 0; t < TT; ++t) {
    const int cur = t & 1, nxt = cur ^ 1;
    xh[j] = (_Float16)xrow[(size_t)t * DH + j];
    __syncthreads();                                     // B1: xh + prev h writes visible

    // layer 0: h0 = tanh(x @ E' + h0p @ Wh0 + b0)
    float a0 = bb0;
    a0 = dot512(Ep, xh, j, a0);
    a0 = dot512(Wh0, h0h[cur], j, a0);
    const float v0 = tanhf(a0);
    h0h[nxt][j] = (_Float16)v0;
    block_stats(v0, red, lane, wave, mu, var);           // B2
    const float o0v = (v0 - mu) * rsqrtf(var + 1e-5f) * gv + bev;
    o0h[j] = (_Float16)o0v;
    __syncthreads();                                     // B3: o0 visible

    // layer 1
    float a1 = bb1;
    a1 = dot512(Wx1, o0h, j, a1);
    a1 = dot512(Wh1, h1h[cur], j, a1);
    const float v1 = tanhf(a1);
    h1h[nxt][j] = (_Float16)v1;
    block_stats(v1, red, lane, wave, mu, var);           // B4
    const float o1v = (v1 - mu) * rsqrtf(var + 1e-5f) * gv + bev;
    o1h[j] = (_Float16)o1v;
    __syncthreads();                                     // B5: o1 visible

    // layer 2
    float a2 = bb2;
    a2 = dot512(Wx2, o1h, j, a2);
    a2 = dot512(Wh2, h2h[cur], j, a2);
    const float v2 = tanhf(a2);
    h2h[nxt][j] = (_Float16)v2;

    if (t == TT - 1) {
      block_stats(v2, red, lane, wave, mu, var);         // B6 (uniform condition)
      o2_out[(size_t)b * DH + j] = (v2 - mu) * rsqrtf(var + 1e-5f) * gv + bev;
    }
  }
}

__global__ __launch_bounds__(64) void clf_kernel(
    const float* __restrict__ o2, const float* __restrict__ w,
    const float* __restrict__ bias, float* __restrict__ out)
{
  const int b = blockIdx.x, d = threadIdx.x;
  const float* ob = o2 + (size_t)b * DH;
  float acc = bias[d];
#pragma unroll 8
  for (int k = 0; k < DH; ++k) acc = fmaf(ob[k], w[(size_t)k * DT + d], acc);
  float m = acc;
#pragma unroll
  for (int off = 32; off > 0; off >>= 1) m = fmaxf(m, __shfl_xor(m, off));
  const float e = expf(acc - m);
  float s = e;
#pragma unroll
  for (int off = 32; off > 0; off >>= 1) s += __shfl_xor(s, off);
  out[(size_t)b * DT + d] = e / s;
}

extern "C" void kernel_launch(void* const* d_in, const int* in_sizes, int n_in,
                              void* d_out, int out_size, void* d_ws, size_t ws_size,
                              hipStream_t stream) {
  const float* inputs = (const float*)d_in[0];
  const float* emb    = (const float*)d_in[1];
  const float* wx0    = (const float*)d_in[2];
  const float* wh0    = (const float*)d_in[3];
  const float* b0     = (const float*)d_in[4];
  const float* wx1    = (const float*)d_in[5];
  const float* wh1    = (const float*)d_in[6];
  const float* b1     = (const float*)d_in[7];
  const float* wx2    = (const float*)d_in[8];
  const float* wh2    = (const float*)d_in[9];
  const float* b2     = (const float*)d_in[10];
  const float* gamma  = (const float*)d_in[11];
  const float* beta   = (const float*)d_in[12];
  const float* clfw   = (const float*)d_in[13];
  const float* clfb   = (const float*)d_in[14];
  float* out = (float*)d_out;

  char* ws = (char*)d_ws;
  const size_t MATB = (size_t)DH * DH * sizeof(_Float16);  // 512 KiB
  _Float16* Ep  = (_Float16*)(ws + 0 * MATB);
  _Float16* Wp  = (_Float16*)(ws + 1 * MATB);   // 5 matrices: Wh0,Wx1,Wh1,Wx2,Wh2
  float*    o2  = (float*)(ws + 6 * MATB);      // 128 KiB

  hipLaunchKernelGGL(eprime_kernel, dim3(512), dim3(512), 0, stream, emb, wx0, Ep);
  hipLaunchKernelGGL(pack_kernel, dim3(DH / 8, 5), dim3(512), 0, stream,
                     wh0, wx1, wh1, wx2, wh2, Wp);
  hipLaunchKernelGGL(rnn_kernel, dim3(BB), dim3(512), 0, stream,
                     inputs,
                     (const h8_t*)Ep,
                     (const h8_t*)(Wp + 0 * (size_t)DH * DH),
                     (const h8_t*)(Wp + 1 * (size_t)DH * DH),
                     (const h8_t*)(Wp + 2 * (size_t)DH * DH),
                     (const h8_t*)(Wp + 3 * (size_t)DH * DH),
                     (const h8_t*)(Wp + 4 * (size_t)DH * DH),
                     b0, b1, b2, gamma, beta, o2);
  hipLaunchKernelGGL(clf_kernel, dim3(BB), dim3(DT), 0, stream, o2, clfw, clfb, out);
}

// Round 3
// 16592.209 us; speedup vs baseline: 5.4001x; 1.4308x over previous
//
#include <hip/hip_runtime.h>

#define DH 512
#define TT 1024
#define BB 64
#define DT 64

typedef _Float16 f16x8 __attribute__((ext_vector_type(8)));
typedef float f32x4 __attribute__((ext_vector_type(4)));

// ---------------------------------------------------------------- precompute

// E' = emb @ wx0 (fp32), E'[e][j]
__global__ __launch_bounds__(512) void eprime_kernel(
    const float* __restrict__ emb, const float* __restrict__ wx0,
    float* __restrict__ Ep)
{
  __shared__ float er[DH];
  const int e = blockIdx.x, j = threadIdx.x;
  er[j] = emb[(size_t)e * DH + j];
  __syncthreads();
  float acc = 0.f;
#pragma unroll 8
  for (int k = 0; k < DH; ++k) acc = fmaf(er[k], wx0[(size_t)k * DH + j], acc);
  Ep[(size_t)e * DH + j] = acc;
}

// packB[m][j][k] = fold_m[k] * src_m[k][j]  (fp16 col-major), m:
// 0=E'(no fold), 1=wh0, 2=wx1(*gamma), 3=wh1, 4=wx2(*gamma), 5=wh2
__global__ __launch_bounds__(512) void pack_kernel(
    const float* __restrict__ Ep, const float* __restrict__ wh0,
    const float* __restrict__ wx1, const float* __restrict__ wh1,
    const float* __restrict__ wx2, const float* __restrict__ wh2,
    const float* __restrict__ gamma, _Float16* __restrict__ dst)
{
  __shared__ float Tt[64][65];
  const int m = blockIdx.z, jt = blockIdx.x, kt = blockIdx.y;
  const float* src = (m == 0) ? Ep : (m == 1) ? wh0 : (m == 2) ? wx1
                   : (m == 3) ? wh1 : (m == 4) ? wx2 : wh2;
  const bool fold = (m == 2 || m == 4);
  const int tx = threadIdx.x & 63, ty = threadIdx.x >> 6;
#pragma unroll
  for (int i = 0; i < 8; ++i) {
    const int k = kt * 64 + ty * 8 + i;
    Tt[ty * 8 + i][tx] = src[(size_t)k * DH + jt * 64 + tx];
  }
  __syncthreads();
#pragma unroll
  for (int i = 0; i < 8; ++i) {
    const int j = jt * 64 + ty * 8 + i;
    const int k = kt * 64 + tx;
    float v = Tt[tx][ty * 8 + i];
    if (fold) v *= gamma[k];
    dst[((size_t)m * DH + j) * DH + k] = (_Float16)v;
  }
}

// bfold[0]=b0; bfold[1]=b1+beta@wx1; bfold[2]=b2+beta@wx2;
// csum[0]=colsum(gamma*wx1); csum[1]=colsum(gamma*wx2);
// clfwf[k][d]=gamma[k]*clfw[k][d]; clfbf=clfb+beta@clfw
__global__ __launch_bounds__(512) void fold_kernel(
    const float* __restrict__ b0, const float* __restrict__ b1,
    const float* __restrict__ b2, const float* __restrict__ wx1,
    const float* __restrict__ wx2, const float* __restrict__ gamma,
    const float* __restrict__ beta, const float* __restrict__ clfw,
    const float* __restrict__ clfb,
    float* __restrict__ bfold, float* __restrict__ csum,
    float* __restrict__ clfwf, float* __restrict__ clfbf)
{
  const int j = threadIdx.x;
  if (blockIdx.x == 0) {
    bfold[j] = b0[j];
    float s1 = 0, s2 = 0, c1 = 0, c2 = 0;
    for (int k = 0; k < DH; ++k) {
      const float w1 = wx1[(size_t)k * DH + j], w2 = wx2[(size_t)k * DH + j];
      s1 += beta[k] * w1;  s2 += beta[k] * w2;
      c1 += gamma[k] * w1; c2 += gamma[k] * w2;
    }
    bfold[DH + j] = b1[j] + s1;
    bfold[2 * DH + j] = b2[j] + s2;
    csum[j] = c1; csum[DH + j] = c2;
  } else {
    for (int idx = j; idx < DH * DT; idx += 512) {
      const int k = idx >> 6, d = idx & 63;
      clfwf[idx] = gamma[k] * clfw[(size_t)k * DT + d];
    }
    if (j < DT) {
      float sb = clfb[j];
      for (int k = 0; k < DH; ++k) sb += beta[k] * clfw[(size_t)k * DT + j];
      clfbf[j] = sb;
    }
  }
}

// ---------------------------------------------------------------- main RNN

__device__ __forceinline__ void spin_ge(unsigned* p, unsigned tgt) {
  while (__hip_atomic_load(p, __ATOMIC_ACQUIRE, __HIP_MEMORY_SCOPE_AGENT) < tgt)
    __builtin_amdgcn_s_sleep(2);
}

// Stage [64x512] fp16 (global, L2) -> LDS [64][520], optional row stats.
__device__ __forceinline__ void stage_h(_Float16* __restrict__ A,
                                        const _Float16* __restrict__ src,
                                        float* muA, float* rsA, bool stats,
                                        int tid)
{
  const int row = tid >> 3, part = tid & 7;
  const f16x8* s = (const f16x8*)(src + (size_t)row * DH);
  float sum = 0.f, sq = 0.f;
#pragma unroll
  for (int i = 0; i < 8; ++i) {
    const f16x8 v = s[i * 8 + part];
    *(f16x8*)(A + row * 520 + (i * 8 + part) * 8) = v;
    if (stats) {
#pragma unroll
      for (int e = 0; e < 8; ++e) { const float f = (float)v[e]; sum += f; sq += f * f; }
    }
  }
  if (stats) {
    sum += __shfl_xor(sum, 1); sq += __shfl_xor(sq, 1);
    sum += __shfl_xor(sum, 2); sq += __shfl_xor(sq, 2);
    sum += __shfl_xor(sum, 4); sq += __shfl_xor(sq, 4);
    if (part == 0) {
      const float mu = sum * (1.f / DH);
      const float var = sq * (1.f / DH) - mu * mu;
      muA[row] = mu; rsA[row] = rsqrtf(var + 1e-5f);
    }
  }
}

// Stage x(t) [64x512] fp32 (HBM) -> LDS fp16 [64][520].
__device__ __forceinline__ void stage_x(_Float16* __restrict__ A,
                                        const float* __restrict__ inputs,
                                        int t, int tid)
{
  const int row = tid >> 3, part = tid & 7;
  const float4* s = (const float4*)(inputs + (size_t)row * TT * DH + (size_t)t * DH);
#pragma unroll
  for (int i = 0; i < 8; ++i) {
    const int u = i * 8 + part;
    const float4 a = s[u * 2], b = s[u * 2 + 1];
    f16x8 v;
    v[0] = (_Float16)a.x; v[1] = (_Float16)a.y; v[2] = (_Float16)a.z; v[3] = (_Float16)a.w;
    v[4] = (_Float16)b.x; v[5] = (_Float16)b.y; v[6] = (_Float16)b.z; v[7] = (_Float16)b.w;
    *(f16x8*)(A + row * 520 + u * 8) = v;
  }
}

// 24 blocks: stage s = bid>>3 (layer), slice c = bid&7 (64 output cols).
// Waves 4M x 2N; B (two 512x64 weight slices) register-resident.
__global__ __launch_bounds__(512, 1) void rnn3_kernel(
    const float* __restrict__ inputs, const _Float16* __restrict__ packB,
    const float* __restrict__ bfold, const float* __restrict__ csum,
    _Float16* __restrict__ h_ex, unsigned* __restrict__ arrive,
    unsigned* __restrict__ consumed)
{
  const int bid = blockIdx.x;
  const int s = bid >> 3, c = bid & 7;
  const int tid = threadIdx.x;
  const int l = tid & 63, w = tid >> 6;
  const int mg = w >> 1, ng = w & 1;

  __shared__ __align__(16) _Float16 A1[64 * 520];
  __shared__ __align__(16) _Float16 A2[64 * 520];
  __shared__ float muS[64], rsS[64];

  // ---- load B into registers (one-time): col j = c*64 + ng*32 + nf*16 + (l&15)
  f16x8 Bx[16][2], Bh[16][2];
  {
    const int colbase = c * 64 + ng * 32 + (l & 15);
    const int kbase = (l >> 4) * 8;
    const _Float16* px = packB + ((size_t)(s * 2 + 0) * DH + colbase) * DH + kbase;
    const _Float16* ph = packB + ((size_t)(s * 2 + 1) * DH + colbase) * DH + kbase;
#pragma unroll
    for (int kk = 0; kk < 16; ++kk) {
#pragma unroll
      for (int nf = 0; nf < 2; ++nf) {
        Bx[kk][nf] = *(const f16x8*)(px + (size_t)nf * 16 * DH + kk * 32);
        Bh[kk][nf] = *(const f16x8*)(ph + (size_t)nf * 16 * DH + kk * 32);
      }
    }
  }

  const int jl0 = c * 64 + ng * 32 + (l & 15), jl1 = jl0 + 16;
  const float b_0 = bfold[s * DH + jl0], b_1 = bfold[s * DH + jl1];
  float cs0 = 0.f, cs1 = 0.f;
  if (s > 0) { cs0 = csum[(s - 1) * DH + jl0]; cs1 = csum[(s - 1) * DH + jl1]; }

  // zero A2 (h_prev = 0 at t=0)
  {
    f16x8 z;
#pragma unroll
    for (int e = 0; e < 8; ++e) z[e] = (_Float16)0.f;
    const int row = tid >> 3, part = tid & 7;
#pragma unroll
    for (int i = 0; i < 8; ++i) *(f16x8*)(A2 + row * 520 + (i * 8 + part) * 8) = z;
  }

  for (int t = 0; t < TT; ++t) {
    // ---- waits (lane 0 of each wave; wave reconverges after)
    if (l == 0) {
      if (s < 2 && t >= 2) spin_ge(consumed + s * TT + (t - 2), 8);
      if (t >= 1)          spin_ge(arrive + s * TT + (t - 1), 8);
      if (s > 0)           spin_ge(arrive + (s - 1) * TT + t, 8);
    }
    // ---- stage operands
    if (t >= 1)
      stage_h(A2, h_ex + (size_t)(s * 2 + ((t - 1) & 1)) * BB * DH, nullptr, nullptr, false, tid);
    if (s == 0)
      stage_x(A1, inputs, t, tid);
    else
      stage_h(A1, h_ex + (size_t)((s - 1) * 2 + (t & 1)) * BB * DH, muS, rsS, true, tid);
    __syncthreads();
    if (s > 0 && tid == 0)
      __hip_atomic_fetch_add(consumed + (s - 1) * TT + t, 1, __ATOMIC_RELEASE, __HIP_MEMORY_SCOPE_AGENT);

    // ---- GEMM: accX = A1 @ Bx, accH = A2 @ Bh  (K = 512)
    f32x4 accX[2], accH[2];
#pragma unroll
    for (int nf = 0; nf < 2; ++nf)
#pragma unroll
      for (int e = 0; e < 4; ++e) { accX[nf][e] = 0.f; accH[nf][e] = 0.f; }

    const _Float16* a1p = A1 + (mg * 16 + (l & 15)) * 520 + (l >> 4) * 8;
    const _Float16* a2p = A2 + (mg * 16 + (l & 15)) * 520 + (l >> 4) * 8;
#pragma unroll
    for (int kk = 0; kk < 16; ++kk) {
      const f16x8 aX = *(const f16x8*)(a1p + kk * 32);
      const f16x8 aH = *(const f16x8*)(a2p + kk * 32);
      accX[0] = __builtin_amdgcn_mfma_f32_16x16x32_f16(aX, Bx[kk][0], accX[0], 0, 0, 0);
      accX[1] = __builtin_amdgcn_mfma_f32_16x16x32_f16(aX, Bx[kk][1], accX[1], 0, 0, 0);
      accH[0] = __builtin_amdgcn_mfma_f32_16x16x32_f16(aH, Bh[kk][0], accH[0], 0, 0, 0);
      accH[1] = __builtin_amdgcn_mfma_f32_16x16x32_f16(aH, Bh[kk][1], accH[1], 0, 0, 0);
    }

    // ---- epilogue: h = tanh(rs*(accX - mu*colsum) + accH + b'), write slice
    _Float16* dst = h_ex + (size_t)(s * 2 + (t & 1)) * BB * DH;
#pragma unroll
    for (int i = 0; i < 4; ++i) {
      const int r = mg * 16 + (l >> 4) * 4 + i;
      const float m1 = (s > 0) ? muS[r] : 0.f;
      const float r1 = (s > 0) ? rsS[r] : 1.f;
      const float p0 = r1 * (accX[0][i] - m1 * cs0) + accH[0][i] + b_0;
      const float p1 = r1 * (accX[1][i] - m1 * cs1) + accH[1][i] + b_1;
      dst[(size_t)r * DH + jl0] = (_Float16)tanhf(p0);
      dst[(size_t)r * DH + jl1] = (_Float16)tanhf(p1);
    }

    // ---- signal
    __syncthreads();
    if (tid == 0) {
      __threadfence();
      __hip_atomic_fetch_add(arrive + s * TT + t, 1, __ATOMIC_RELEASE, __HIP_MEMORY_SCOPE_AGENT);
    }
  }
}

// ---------------------------------------------------------------- classifier

__global__ __launch_bounds__(64) void clf_kernel(
    const _Float16* __restrict__ h2, const float* __restrict__ clfwf,
    const float* __restrict__ clfbf, float* __restrict__ out)
{
  const int b = blockIdx.x, d = threadIdx.x;
  __shared__ float o2[DH];
  const _Float16* hrow = h2 + (size_t)b * DH;
  float sum = 0.f, sq = 0.f;
#pragma unroll
  for (int i = 0; i < 8; ++i) {
    const float v = (float)hrow[d * 8 + i];
    sum += v; sq += v * v;
  }
#pragma unroll
  for (int off = 32; off; off >>= 1) { sum += __shfl_xor(sum, off); sq += __shfl_xor(sq, off); }
  const float mu = sum * (1.f / DH);
  const float rs = rsqrtf(sq * (1.f / DH) - mu * mu + 1e-5f);
#pragma unroll
  for (int i = 0; i < 8; ++i) o2[d * 8 + i] = ((float)hrow[d * 8 + i] - mu) * rs;
  __syncthreads();
  float acc = clfbf[d];
#pragma unroll 8
  for (int k = 0; k < DH; ++k) acc = fmaf(o2[k], clfwf[k * DT + d], acc);
  float mx = acc;
#pragma unroll
  for (int off = 32; off; off >>= 1) mx = fmaxf(mx, __shfl_xor(mx, off));
  const float e = expf(acc - mx);
  float ss = e;
#pragma unroll
  for (int off = 32; off; off >>= 1) ss += __shfl_xor(ss, off);
  out[(size_t)b * DT + d] = e / ss;
}

// ---------------------------------------------------------------- launch

extern "C" void kernel_launch(void* const* d_in, const int* in_sizes, int n_in,
                              void* d_out, int out_size, void* d_ws, size_t ws_size,
                              hipStream_t stream) {
  const float* inputs = (const float*)d_in[0];
  const float* emb    = (const float*)d_in[1];
  const float* wx0    = (const float*)d_in[2];
  const float* wh0    = (const float*)d_in[3];
  const float* b0     = (const float*)d_in[4];
  const float* wx1    = (const float*)d_in[5];
  const float* wh1    = (const float*)d_in[6];
  const float* b1     = (const float*)d_in[7];
  const float* wx2    = (const float*)d_in[8];
  const float* wh2    = (const float*)d_in[9];
  const float* b2     = (const float*)d_in[10];
  const float* gamma  = (const float*)d_in[11];
  const float* beta   = (const float*)d_in[12];
  const float* clfw   = (const float*)d_in[13];
  const float* clfb   = (const float*)d_in[14];
  float* out = (float*)d_out;

  char* ws = (char*)d_ws;
  size_t off = 0;
  float*    Ep    = (float*)(ws + off);    off += (size_t)DH * DH * 4;          // 1 MB
  _Float16* packB = (_Float16*)(ws + off); off += (size_t)6 * DH * DH * 2;      // 3 MB
  _Float16* h_ex  = (_Float16*)(ws + off); off += (size_t)3 * 2 * BB * DH * 2;  // 384 KB
  float*    bfold = (float*)(ws + off);    off += (size_t)3 * DH * 4;
  float*    csumP = (float*)(ws + off);    off += (size_t)2 * DH * 4;
  float*    clfwf = (float*)(ws + off);    off += (size_t)DH * DT * 4;          // 128 KB
  float*    clfbf = (float*)(ws + off);    off += 256;
  unsigned* flags = (unsigned*)(ws + off);                                      // arrive+consumed
  unsigned* arrive   = flags;
  unsigned* consumed = flags + 3 * TT;
  const size_t flag_bytes = (size_t)(3 + 2) * TT * 4;

  hipMemsetAsync(flags, 0, flag_bytes, stream);
  hipLaunchKernelGGL(eprime_kernel, dim3(DH), dim3(512), 0, stream, emb, wx0, Ep);
  hipLaunchKernelGGL(pack_kernel, dim3(8, 8, 6), dim3(512), 0, stream,
                     Ep, wh0, wx1, wh1, wx2, wh2, gamma, packB);
  hipLaunchKernelGGL(fold_kernel, dim3(2), dim3(512), 0, stream,
                     b0, b1, b2, wx1, wx2, gamma, beta, clfw, clfb,
                     bfold, csumP, clfwf, clfbf);
  hipLaunchKernelGGL(rnn3_kernel, dim3(24), dim3(512), 0, stream,
                     inputs, packB, bfold, csumP, h_ex, arrive, consumed);
  // final h2 lives in slot (1023 & 1) = 1 of stage 2
  const _Float16* h2fin = h_ex + (size_t)(2 * 2 + 1) * BB * DH;
  hipLaunchKernelGGL(clf_kernel, dim3(BB), dim3(DT), 0, stream,
                     h2fin, clfwf, clfbf, out);
}

// Round 5
// 13582.344 us; speedup vs baseline: 6.5967x; 1.2216x over previous
//
#include <hip/hip_runtime.h>

#define DH 512
#define TT 1024
#define BB 64
#define DT 64
#define RD 4  // h_ex ring depth

typedef _Float16 f16x8 __attribute__((ext_vector_type(8)));
typedef float f32x4 __attribute__((ext_vector_type(4)));

// LDS A-tile subtile layout: element (row r, k) at A[((k>>3)*65 + r)*8 + (k&7)]
// bank group = (ks + row) % 8 -> conflict-free for both stagers and MFMA readers.
#define ATILE_HALVES (64 * 65 * 8)

// ---------------------------------------------------------------- precompute

// E' = emb @ wx0 (fp32), E'[e][j]
__global__ __launch_bounds__(512) void eprime_kernel(
    const float* __restrict__ emb, const float* __restrict__ wx0,
    float* __restrict__ Ep)
{
  __shared__ float er[DH];
  const int e = blockIdx.x, j = threadIdx.x;
  er[j] = emb[(size_t)e * DH + j];
  __syncthreads();
  float acc = 0.f;
#pragma unroll 8
  for (int k = 0; k < DH; ++k) acc = fmaf(er[k], wx0[(size_t)k * DH + j], acc);
  Ep[(size_t)e * DH + j] = acc;
}

// packB[m][j][k] = fold_m[k] * src_m[k][j]  (fp16 col-major), m:
// 0=E'(no fold), 1=wh0, 2=wx1(*gamma), 3=wh1, 4=wx2(*gamma), 5=wh2
__global__ __launch_bounds__(512) void pack_kernel(
    const float* __restrict__ Ep, const float* __restrict__ wh0,
    const float* __restrict__ wx1, const float* __restrict__ wh1,
    const float* __restrict__ wx2, const float* __restrict__ wh2,
    const float* __restrict__ gamma, _Float16* __restrict__ dst)
{
  __shared__ float Tt[64][65];
  const int m = blockIdx.z, jt = blockIdx.x, kt = blockIdx.y;
  const float* src = (m == 0) ? Ep : (m == 1) ? wh0 : (m == 2) ? wx1
                   : (m == 3) ? wh1 : (m == 4) ? wx2 : wh2;
  const bool fold = (m == 2 || m == 4);
  const int tx = threadIdx.x & 63, ty = threadIdx.x >> 6;
#pragma unroll
  for (int i = 0; i < 8; ++i) {
    const int k = kt * 64 + ty * 8 + i;
    Tt[ty * 8 + i][tx] = src[(size_t)k * DH + jt * 64 + tx];
  }
  __syncthreads();
#pragma unroll
  for (int i = 0; i < 8; ++i) {
    const int j = jt * 64 + ty * 8 + i;
    const int k = kt * 64 + tx;
    float v = Tt[tx][ty * 8 + i];
    if (fold) v *= gamma[k];
    dst[((size_t)m * DH + j) * DH + k] = (_Float16)v;
  }
}

__global__ __launch_bounds__(512) void fold_kernel(
    const float* __restrict__ b0, const float* __restrict__ b1,
    const float* __restrict__ b2, const float* __restrict__ wx1,
    const float* __restrict__ wx2, const float* __restrict__ gamma,
    const float* __restrict__ beta, const float* __restrict__ clfw,
    const float* __restrict__ clfb,
    float* __restrict__ bfold, float* __restrict__ csum,
    float* __restrict__ clfwf, float* __restrict__ clfbf)
{
  const int j = threadIdx.x;
  if (blockIdx.x == 0) {
    bfold[j] = b0[j];
    float s1 = 0, s2 = 0, c1 = 0, c2 = 0;
    for (int k = 0; k < DH; ++k) {
      const float w1 = wx1[(size_t)k * DH + j], w2 = wx2[(size_t)k * DH + j];
      s1 += beta[k] * w1;  s2 += beta[k] * w2;
      c1 += gamma[k] * w1; c2 += gamma[k] * w2;
    }
    bfold[DH + j] = b1[j] + s1;
    bfold[2 * DH + j] = b2[j] + s2;
    csum[j] = c1; csum[DH + j] = c2;
  } else {
    for (int idx = j; idx < DH * DT; idx += 512) {
      const int k = idx >> 6, d = idx & 63;
      clfwf[idx] = gamma[k] * clfw[(size_t)k * DT + d];
    }
    if (j < DT) {
      float sb = clfb[j];
      for (int k = 0; k < DH; ++k) sb += beta[k] * clfw[(size_t)k * DT + j];
      clfbf[j] = sb;
    }
  }
}

// v_all[t][b][j] (fp16) = sum_e x[b][t][e] * E'[e][j];  one block per t.
__global__ __launch_bounds__(512, 1) void vgemm_kernel(
    const float* __restrict__ x, const _Float16* __restrict__ Bt,
    _Float16* __restrict__ v)
{
  const int t = blockIdx.x;
  const int tid = threadIdx.x, l = tid & 63, w = tid >> 6;
  __shared__ __align__(16) _Float16 A[ATILE_HALVES];
  {
    const int row = tid >> 3, part = tid & 7;
    const float4* sp = (const float4*)(x + ((size_t)row * TT + t) * DH);
#pragma unroll
    for (int i = 0; i < 8; ++i) {
      const int ks = i * 8 + part;
      const float4 a = sp[ks * 2], b = sp[ks * 2 + 1];
      f16x8 vv;
      vv[0] = (_Float16)a.x; vv[1] = (_Float16)a.y; vv[2] = (_Float16)a.z; vv[3] = (_Float16)a.w;
      vv[4] = (_Float16)b.x; vv[5] = (_Float16)b.y; vv[6] = (_Float16)b.z; vv[7] = (_Float16)b.w;
      *(f16x8*)(A + ((size_t)ks * 65 + row) * 8) = vv;
    }
  }
  __syncthreads();
  const int jb = w * 64;
  const int arowb = l & 15, g = l >> 4;
  f32x4 acc[4][4];
#pragma unroll
  for (int mf = 0; mf < 4; ++mf)
#pragma unroll
    for (int nf = 0; nf < 4; ++nf)
#pragma unroll
      for (int e = 0; e < 4; ++e) acc[mf][nf][e] = 0.f;
#pragma unroll
  for (int kk = 0; kk < 16; ++kk) {
    const int ks = kk * 4 + g;
    f16x8 am[4], bn[4];
#pragma unroll
    for (int mf = 0; mf < 4; ++mf)
      am[mf] = *(const f16x8*)(A + ((size_t)ks * 65 + mf * 16 + arowb) * 8);
#pragma unroll
    for (int nf = 0; nf < 4; ++nf)
      bn[nf] = *(const f16x8*)(Bt + (size_t)(jb + nf * 16 + arowb) * DH + kk * 32 + g * 8);
#pragma unroll
    for (int mf = 0; mf < 4; ++mf)
#pragma unroll
      for (int nf = 0; nf < 4; ++nf)
        acc[mf][nf] = __builtin_amdgcn_mfma_f32_16x16x32_f16(am[mf], bn[nf], acc[mf][nf], 0, 0, 0);
  }
#pragma unroll
  for (int mf = 0; mf < 4; ++mf)
#pragma unroll
    for (int nf = 0; nf < 4; ++nf)
#pragma unroll
      for (int i = 0; i < 4; ++i) {
        const int r = mf * 16 + (l >> 4) * 4 + i;
        const int j = jb + nf * 16 + (l & 15);
        v[((size_t)t * BB + r) * DH + j] = (_Float16)acc[mf][nf][i];
      }
}

// ---------------------------------------------------------------- main RNN

__device__ __forceinline__ void stage_h(_Float16* __restrict__ A,
                                        const _Float16* __restrict__ src,
                                        float* muA, float* rsA, bool stats,
                                        int tid)
{
  const int row = tid >> 3, part = tid & 7;
  const f16x8* sp = (const f16x8*)(src + (size_t)row * DH);
  float sum = 0.f, sq = 0.f;
#pragma unroll
  for (int i = 0; i < 8; ++i) {
    const int ks = i * 8 + part;
    const f16x8 vv = sp[ks];
    *(f16x8*)(A + ((size_t)ks * 65 + row) * 8) = vv;
    if (stats) {
#pragma unroll
      for (int e = 0; e < 8; ++e) { const float f = (float)vv[e]; sum += f; sq += f * f; }
    }
  }
  if (stats) {
    sum += __shfl_xor(sum, 1); sq += __shfl_xor(sq, 1);
    sum += __shfl_xor(sum, 2); sq += __shfl_xor(sq, 2);
    sum += __shfl_xor(sum, 4); sq += __shfl_xor(sq, 4);
    if (part == 0) {
      const float mu = sum * (1.f / DH);
      const float var = sq * (1.f / DH) - mu * mu;
      muA[row] = mu; rsA[row] = rsqrtf(var + 1e-5f);
    }
  }
}

__device__ __forceinline__ void stage_x(_Float16* __restrict__ A,
                                        const float* __restrict__ inputs,
                                        int t, int tid)
{
  const int row = tid >> 3, part = tid & 7;
  const float4* sp = (const float4*)(inputs + ((size_t)row * TT + t) * DH);
#pragma unroll
  for (int i = 0; i < 8; ++i) {
    const int ks = i * 8 + part;
    const float4 a = sp[ks * 2], b = sp[ks * 2 + 1];
    f16x8 vv;
    vv[0] = (_Float16)a.x; vv[1] = (_Float16)a.y; vv[2] = (_Float16)a.z; vv[3] = (_Float16)a.w;
    vv[4] = (_Float16)b.x; vv[5] = (_Float16)b.y; vv[6] = (_Float16)b.z; vv[7] = (_Float16)b.w;
    *(f16x8*)(A + ((size_t)ks * 65 + row) * 8) = vv;
  }
}

// 24 blocks: stage s = bid>>3 (layer), slice c = bid&7 (64 output cols).
__global__ __launch_bounds__(512, 1) void rnn4_kernel(
    const float* __restrict__ inputs, const _Float16* __restrict__ v_all,
    const int use_v, const _Float16* __restrict__ packB,
    const float* __restrict__ bfold, const float* __restrict__ csum,
    _Float16* __restrict__ h_ex, unsigned* __restrict__ arr,
    unsigned* __restrict__ cons)
{
  const int bid = blockIdx.x;
  const int s = bid >> 3, c = bid & 7;
  const int tid = threadIdx.x;
  const int l = tid & 63, w = tid >> 6;
  const int mg = w >> 1, ng = w & 1;

  __shared__ __align__(16) _Float16 A1[ATILE_HALVES];
  __shared__ __align__(16) _Float16 A2[ATILE_HALVES];
  __shared__ float muS[64], rsS[64];

  const bool sx = (s == 0);
  const bool havev = (use_v != 0);
  const bool needX = (!sx || !havev);

  // ---- one-time register-resident B slices
  f16x8 Bx[16][2], Bh[16][2];
  const int colbase = c * 64 + ng * 32 + (l & 15);
  const int kbase = (l >> 4) * 8;
  {
    const _Float16* ph = packB + ((size_t)(s * 2 + 1) * DH + colbase) * DH + kbase;
#pragma unroll
    for (int kk = 0; kk < 16; ++kk)
#pragma unroll
      for (int nf = 0; nf < 2; ++nf)
        Bh[kk][nf] = *(const f16x8*)(ph + (size_t)nf * 16 * DH + kk * 32);
  }
  if (needX) {
    const _Float16* px = packB + ((size_t)(s * 2 + 0) * DH + colbase) * DH + kbase;
#pragma unroll
    for (int kk = 0; kk < 16; ++kk)
#pragma unroll
      for (int nf = 0; nf < 2; ++nf)
        Bx[kk][nf] = *(const f16x8*)(px + (size_t)nf * 16 * DH + kk * 32);
  }

  const int jl0 = colbase, jl1 = colbase + 16;
  const float b_0 = bfold[s * DH + jl0], b_1 = bfold[s * DH + jl1];
  float cs0 = 0.f, cs1 = 0.f;
  if (s > 0) { cs0 = csum[(s - 1) * DH + jl0]; cs1 = csum[(s - 1) * DH + jl1]; }

  // zero A2 (h_prev = 0 at t=0)
  {
    f16x8 z;
#pragma unroll
    for (int e = 0; e < 8; ++e) z[e] = (_Float16)0.f;
#pragma unroll
    for (int q = 0; q < 9; ++q) {
      const int gidx = q * 512 + tid;
      if (gidx < 64 * 65) *(f16x8*)(A2 + (size_t)gidx * 8) = z;
    }
  }

  for (int t = 0; t < TT; ++t) {
    // ---- poll flags: wave 0, 24 lanes in parallel, RELAXED loads (no inv storm)
    if (w == 0) {
      const int li = l & 7, grp = l >> 3;
      unsigned* p = nullptr; unsigned tgt = 0;
      if (grp == 0 && t >= 1)                   { p = arr  + (s * 8 + li) * 16;        tgt = (unsigned)t; }
      else if (grp == 1 && s > 0)               { p = arr  + ((s - 1) * 8 + li) * 16;  tgt = (unsigned)(t + 1); }
      else if (grp == 2 && s < 2 && t >= RD)    { p = cons + (s * 8 + li) * 16;        tgt = (unsigned)(t - RD + 1); }
      while (true) {
        bool mine = true;
        if (p) mine = (__hip_atomic_load(p, __ATOMIC_RELAXED, __HIP_MEMORY_SCOPE_AGENT) >= tgt);
        if (__all(mine)) break;
        __builtin_amdgcn_s_sleep(4);
      }
    }
    __syncthreads();
    __builtin_amdgcn_fence(__ATOMIC_ACQUIRE, "agent");  // ONE L2-inv per step

    // ---- stage operands
    if (t >= 1)
      stage_h(A2, h_ex + (size_t)(s * RD + ((t - 1) & (RD - 1))) * BB * DH,
              nullptr, nullptr, false, tid);
    if (!sx)
      stage_h(A1, h_ex + (size_t)((s - 1) * RD + (t & (RD - 1))) * BB * DH,
              muS, rsS, true, tid);
    else if (!havev)
      stage_x(A1, inputs, t, tid);
    __syncthreads();
    if (tid == 0 && s > 0)   // loads done (barrier drained vmcnt) -> relaxed is safe
      __hip_atomic_store(cons + ((s - 1) * 8 + c) * 16, (unsigned)(t + 1),
                         __ATOMIC_RELAXED, __HIP_MEMORY_SCOPE_AGENT);

    // ---- GEMM (K = 512)
    f32x4 accX[2], accH[2];
#pragma unroll
    for (int nf = 0; nf < 2; ++nf)
#pragma unroll
      for (int e = 0; e < 4; ++e) { accX[nf][e] = 0.f; accH[nf][e] = 0.f; }
    const int arow = mg * 16 + (l & 15);
    const int g = l >> 4;
#pragma unroll
    for (int kk = 0; kk < 16; ++kk) {
      const int ks = kk * 4 + g;
      const f16x8 aH = *(const f16x8*)(A2 + ((size_t)ks * 65 + arow) * 8);
      accH[0] = __builtin_amdgcn_mfma_f32_16x16x32_f16(aH, Bh[kk][0], accH[0], 0, 0, 0);
      accH[1] = __builtin_amdgcn_mfma_f32_16x16x32_f16(aH, Bh[kk][1], accH[1], 0, 0, 0);
      if (needX) {
        const f16x8 aX = *(const f16x8*)(A1 + ((size_t)ks * 65 + arow) * 8);
        accX[0] = __builtin_amdgcn_mfma_f32_16x16x32_f16(aX, Bx[kk][0], accX[0], 0, 0, 0);
        accX[1] = __builtin_amdgcn_mfma_f32_16x16x32_f16(aX, Bx[kk][1], accX[1], 0, 0, 0);
      }
    }

    // ---- epilogue: h = tanh(...), write slice
    _Float16* dst = h_ex + (size_t)(s * RD + (t & (RD - 1))) * BB * DH;
#pragma unroll
    for (int i = 0; i < 4; ++i) {
      const int r = mg * 16 + (l >> 4) * 4 + i;
      float p0, p1;
      if (sx) {
        float v0, v1;
        if (havev) {
          v0 = (float)v_all[((size_t)t * BB + r) * DH + jl0];
          v1 = (float)v_all[((size_t)t * BB + r) * DH + jl1];
        } else { v0 = accX[0][i]; v1 = accX[1][i]; }
        p0 = v0 + accH[0][i] + b_0;
        p1 = v1 + accH[1][i] + b_1;
      } else {
        const float m1 = muS[r], r1 = rsS[r];
        p0 = r1 * (accX[0][i] - m1 * cs0) + accH[0][i] + b_0;
        p1 = r1 * (accX[1][i] - m1 * cs1) + accH[1][i] + b_1;
      }
      dst[(size_t)r * DH + jl0] = (_Float16)tanhf(p0);
      dst[(size_t)r * DH + jl1] = (_Float16)tanhf(p1);
    }

    // ---- signal: barrier drains all waves' stores, then ONE release store (wbl2)
    __syncthreads();
    if (tid == 0)
      __hip_atomic_store(arr + (s * 8 + c) * 16, (unsigned)(t + 1),
                         __ATOMIC_RELEASE, __HIP_MEMORY_SCOPE_AGENT);
  }
}

// ---------------------------------------------------------------- classifier

__global__ __launch_bounds__(64) void clf_kernel(
    const _Float16* __restrict__ h2, const float* __restrict__ clfwf,
    const float* __restrict__ clfbf, float* __restrict__ out)
{
  const int b = blockIdx.x, d = threadIdx.x;
  __shared__ float o2[DH];
  const _Float16* hrow = h2 + (size_t)b * DH;
  float sum = 0.f, sq = 0.f;
#pragma unroll
  for (int i = 0; i < 8; ++i) {
    const float v = (float)hrow[d * 8 + i];
    sum += v; sq += v * v;
  }
#pragma unroll
  for (int off = 32; off; off >>= 1) { sum += __shfl_xor(sum, off); sq += __shfl_xor(sq, off); }
  const float mu = sum * (1.f / DH);
  const float rs = rsqrtf(sq * (1.f / DH) - mu * mu + 1e-5f);
#pragma unroll
  for (int i = 0; i < 8; ++i) o2[d * 8 + i] = ((float)hrow[d * 8 + i] - mu) * rs;
  __syncthreads();
  float acc = clfbf[d];
#pragma unroll 8
  for (int k = 0; k < DH; ++k) acc = fmaf(o2[k], clfwf[k * DT + d], acc);
  float mx = acc;
#pragma unroll
  for (int off = 32; off; off >>= 1) mx = fmaxf(mx, __shfl_xor(mx, off));
  const float e = expf(acc - mx);
  float ss = e;
#pragma unroll
  for (int off = 32; off; off >>= 1) ss += __shfl_xor(ss, off);
  out[(size_t)b * DT + d] = e / ss;
}

// ---------------------------------------------------------------- launch

extern "C" void kernel_launch(void* const* d_in, const int* in_sizes, int n_in,
                              void* d_out, int out_size, void* d_ws, size_t ws_size,
                              hipStream_t stream) {
  const float* inputs = (const float*)d_in[0];
  const float* emb    = (const float*)d_in[1];
  const float* wx0    = (const float*)d_in[2];
  const float* wh0    = (const float*)d_in[3];
  const float* b0     = (const float*)d_in[4];
  const float* wx1    = (const float*)d_in[5];
  const float* wh1    = (const float*)d_in[6];
  const float* b1     = (const float*)d_in[7];
  const float* wx2    = (const float*)d_in[8];
  const float* wh2    = (const float*)d_in[9];
  const float* b2     = (const float*)d_in[10];
  const float* gamma  = (const float*)d_in[11];
  const float* beta   = (const float*)d_in[12];
  const float* clfw   = (const float*)d_in[13];
  const float* clfb   = (const float*)d_in[14];
  float* out = (float*)d_out;

  char* ws = (char*)d_ws;
  size_t off = 0;
  float*    Ep    = (float*)(ws + off);    off += (size_t)DH * DH * 4;               // 1 MB
  _Float16* packB = (_Float16*)(ws + off); off += (size_t)6 * DH * DH * 2;           // 3 MB
  _Float16* h_ex  = (_Float16*)(ws + off); off += (size_t)3 * RD * BB * DH * 2;      // 768 KB
  float*    bfold = (float*)(ws + off);    off += (size_t)3 * DH * 4;
  float*    csumP = (float*)(ws + off);    off += (size_t)2 * DH * 4;
  float*    clfwf = (float*)(ws + off);    off += (size_t)DH * DT * 4;               // 128 KB
  float*    clfbf = (float*)(ws + off);    off += 256;
  unsigned* arr   = (unsigned*)(ws + off); off += (size_t)3 * 8 * 16 * 4;            // 1.5 KB
  unsigned* cons  = (unsigned*)(ws + off); off += (size_t)2 * 8 * 16 * 4;            // 1 KB
  off = (off + 255) & ~(size_t)255;
  _Float16* v_all = (_Float16*)(ws + off);
  const size_t need_v = off + (size_t)TT * BB * DH * 2;                              // +64 MB
  const int use_v = (ws_size >= need_v) ? 1 : 0;

  (void)hipMemsetAsync(arr, 0, (size_t)(3 * 8 * 16 + 2 * 8 * 16) * 4, stream);
  hipLaunchKernelGGL(eprime_kernel, dim3(DH), dim3(512), 0, stream, emb, wx0, Ep);
  hipLaunchKernelGGL(pack_kernel, dim3(8, 8, 6), dim3(512), 0, stream,
                     Ep, wh0, wx1, wh1, wx2, wh2, gamma, packB);
  hipLaunchKernelGGL(fold_kernel, dim3(2), dim3(512), 0, stream,
                     b0, b1, b2, wx1, wx2, gamma, beta, clfw, clfb,
                     bfold, csumP, clfwf, clfbf);
  if (use_v)
    hipLaunchKernelGGL(vgemm_kernel, dim3(TT), dim3(512), 0, stream,
                       inputs, packB, v_all);
  hipLaunchKernelGGL(rnn4_kernel, dim3(24), dim3(512), 0, stream,
                     inputs, v_all, use_v, packB, bfold, csumP, h_ex, arr, cons);
  // final h2 lives in slot (1023 & (RD-1)) = 3 of stage 2
  const _Float16* h2fin = h_ex + (size_t)(2 * RD + ((TT - 1) & (RD - 1))) * BB * DH;
  hipLaunchKernelGGL(clf_kernel, dim3(BB), dim3(DT), 0, stream,
                     h2fin, clfwf, clfbf, out);
}

// Round 6
// 10297.327 us; speedup vs baseline: 8.7012x; 1.3190x over previous
//
#include <hip/hip_runtime.h>

#define DH 512
#define TT 1024
#define BB 64
#define DT 64
#define RD 4  // h_ex ring depth

typedef _Float16 f16x8 __attribute__((ext_vector_type(8)));
typedef float f32x4 __attribute__((ext_vector_type(4)));

// LDS A-tile subtile layout: element (row r, k) at A[((k>>3)*65 + r)*8 + (k&7)]
#define ATILE_HALVES (64 * 65 * 8)

// Coherent (LLC-level, sc0 sc1) accesses via volatile — bypass non-coherent L2.
__device__ __forceinline__ f16x8 cload(const _Float16* p) {
  return *(const volatile f16x8*)p;
}
__device__ __forceinline__ void cstore(_Float16* p, f16x8 v) {
  *(volatile f16x8*)p = v;
}

// ---------------------------------------------------------------- precompute

__global__ __launch_bounds__(512) void eprime_kernel(
    const float* __restrict__ emb, const float* __restrict__ wx0,
    float* __restrict__ Ep)
{
  __shared__ float er[DH];
  const int e = blockIdx.x, j = threadIdx.x;
  er[j] = emb[(size_t)e * DH + j];
  __syncthreads();
  float acc = 0.f;
#pragma unroll 8
  for (int k = 0; k < DH; ++k) acc = fmaf(er[k], wx0[(size_t)k * DH + j], acc);
  Ep[(size_t)e * DH + j] = acc;
}

// packB[m][j][k] = fold_m[k] * src_m[k][j]  (fp16 col-major)
__global__ __launch_bounds__(512) void pack_kernel(
    const float* __restrict__ Ep, const float* __restrict__ wh0,
    const float* __restrict__ wx1, const float* __restrict__ wh1,
    const float* __restrict__ wx2, const float* __restrict__ wh2,
    const float* __restrict__ gamma, _Float16* __restrict__ dst)
{
  __shared__ float Tt[64][65];
  const int m = blockIdx.z, jt = blockIdx.x, kt = blockIdx.y;
  const float* src = (m == 0) ? Ep : (m == 1) ? wh0 : (m == 2) ? wx1
                   : (m == 3) ? wh1 : (m == 4) ? wx2 : wh2;
  const bool fold = (m == 2 || m == 4);
  const int tx = threadIdx.x & 63, ty = threadIdx.x >> 6;
#pragma unroll
  for (int i = 0; i < 8; ++i) {
    const int k = kt * 64 + ty * 8 + i;
    Tt[ty * 8 + i][tx] = src[(size_t)k * DH + jt * 64 + tx];
  }
  __syncthreads();
#pragma unroll
  for (int i = 0; i < 8; ++i) {
    const int j = jt * 64 + ty * 8 + i;
    const int k = kt * 64 + tx;
    float v = Tt[tx][ty * 8 + i];
    if (fold) v *= gamma[k];
    dst[((size_t)m * DH + j) * DH + k] = (_Float16)v;
  }
}

__global__ __launch_bounds__(512) void fold_kernel(
    const float* __restrict__ b0, const float* __restrict__ b1,
    const float* __restrict__ b2, const float* __restrict__ wx1,
    const float* __restrict__ wx2, const float* __restrict__ gamma,
    const float* __restrict__ beta, const float* __restrict__ clfw,
    const float* __restrict__ clfb,
    float* __restrict__ bfold, float* __restrict__ csum,
    float* __restrict__ clfwf, float* __restrict__ clfbf)
{
  const int j = threadIdx.x;
  if (blockIdx.x == 0) {
    bfold[j] = b0[j];
    float s1 = 0, s2 = 0, c1 = 0, c2 = 0;
    for (int k = 0; k < DH; ++k) {
      const float w1 = wx1[(size_t)k * DH + j], w2 = wx2[(size_t)k * DH + j];
      s1 += beta[k] * w1;  s2 += beta[k] * w2;
      c1 += gamma[k] * w1; c2 += gamma[k] * w2;
    }
    bfold[DH + j] = b1[j] + s1;
    bfold[2 * DH + j] = b2[j] + s2;
    csum[j] = c1; csum[DH + j] = c2;
  } else {
    for (int idx = j; idx < DH * DT; idx += 512) {
      const int k = idx >> 6, d = idx & 63;
      clfwf[idx] = gamma[k] * clfw[(size_t)k * DT + d];
    }
    if (j < DT) {
      float sb = clfb[j];
      for (int k = 0; k < DH; ++k) sb += beta[k] * clfw[(size_t)k * DT + j];
      clfbf[j] = sb;
    }
  }
}

// v_all[t][b][j] (fp16) = sum_e x[b][t][e] * E'[e][j];  one block per t.
__global__ __launch_bounds__(512, 1) void vgemm_kernel(
    const float* __restrict__ x, const _Float16* __restrict__ Bt,
    _Float16* __restrict__ v)
{
  const int t = blockIdx.x;
  const int tid = threadIdx.x, l = tid & 63, w = tid >> 6;
  __shared__ __align__(16) _Float16 A[ATILE_HALVES];
  {
    const int row = tid >> 3, part = tid & 7;
    const float4* sp = (const float4*)(x + ((size_t)row * TT + t) * DH);
#pragma unroll
    for (int i = 0; i < 8; ++i) {
      const int ks = i * 8 + part;
      const float4 a = sp[ks * 2], b = sp[ks * 2 + 1];
      f16x8 vv;
      vv[0] = (_Float16)a.x; vv[1] = (_Float16)a.y; vv[2] = (_Float16)a.z; vv[3] = (_Float16)a.w;
      vv[4] = (_Float16)b.x; vv[5] = (_Float16)b.y; vv[6] = (_Float16)b.z; vv[7] = (_Float16)b.w;
      *(f16x8*)(A + ((size_t)ks * 65 + row) * 8) = vv;
    }
  }
  __syncthreads();
  const int jb = w * 64;
  const int arowb = l & 15, g = l >> 4;
  f32x4 acc[4][4];
#pragma unroll
  for (int mf = 0; mf < 4; ++mf)
#pragma unroll
    for (int nf = 0; nf < 4; ++nf)
#pragma unroll
      for (int e = 0; e < 4; ++e) acc[mf][nf][e] = 0.f;
#pragma unroll
  for (int kk = 0; kk < 16; ++kk) {
    const int ks = kk * 4 + g;
    f16x8 am[4], bn[4];
#pragma unroll
    for (int mf = 0; mf < 4; ++mf)
      am[mf] = *(const f16x8*)(A + ((size_t)ks * 65 + mf * 16 + arowb) * 8);
#pragma unroll
    for (int nf = 0; nf < 4; ++nf)
      bn[nf] = *(const f16x8*)(Bt + (size_t)(jb + nf * 16 + arowb) * DH + kk * 32 + g * 8);
#pragma unroll
    for (int mf = 0; mf < 4; ++mf)
#pragma unroll
      for (int nf = 0; nf < 4; ++nf)
        acc[mf][nf] = __builtin_amdgcn_mfma_f32_16x16x32_f16(am[mf], bn[nf], acc[mf][nf], 0, 0, 0);
  }
#pragma unroll
  for (int mf = 0; mf < 4; ++mf)
#pragma unroll
    for (int nf = 0; nf < 4; ++nf)
#pragma unroll
      for (int i = 0; i < 4; ++i) {
        const int r = mf * 16 + (l >> 4) * 4 + i;
        const int j = jb + nf * 16 + (l & 15);
        v[((size_t)t * BB + r) * DH + j] = (_Float16)acc[mf][nf][i];
      }
}

// ---------------------------------------------------------------- main RNN

// Coherent-stage [64x512] fp16 (LLC) -> LDS, optional row stats.
__device__ __forceinline__ void stage_hv(_Float16* __restrict__ A,
                                         const _Float16* __restrict__ src,
                                         float* muA, float* rsA, bool stats,
                                         int tid)
{
  const int row = tid >> 3, part = tid & 7;
  const _Float16* sp = src + (size_t)row * DH;
  f16x8 v[8];
#pragma unroll
  for (int i = 0; i < 8; ++i) v[i] = cload(sp + (size_t)(i * 8 + part) * 8);
  float sum = 0.f, sq = 0.f;
#pragma unroll
  for (int i = 0; i < 8; ++i) {
    const int ks = i * 8 + part;
    *(f16x8*)(A + ((size_t)ks * 65 + row) * 8) = v[i];
    if (stats) {
#pragma unroll
      for (int e = 0; e < 8; ++e) { const float f = (float)v[i][e]; sum += f; sq += f * f; }
    }
  }
  if (stats) {
    sum += __shfl_xor(sum, 1); sq += __shfl_xor(sq, 1);
    sum += __shfl_xor(sum, 2); sq += __shfl_xor(sq, 2);
    sum += __shfl_xor(sum, 4); sq += __shfl_xor(sq, 4);
    if (part == 0) {
      const float mu = sum * (1.f / DH);
      const float var = sq * (1.f / DH) - mu * mu;
      muA[row] = mu; rsA[row] = rsqrtf(var + 1e-5f);
    }
  }
}

__device__ __forceinline__ void stage_x(_Float16* __restrict__ A,
                                        const float* __restrict__ inputs,
                                        int t, int tid)
{
  const int row = tid >> 3, part = tid & 7;
  const float4* sp = (const float4*)(inputs + ((size_t)row * TT + t) * DH);
#pragma unroll
  for (int i = 0; i < 8; ++i) {
    const int ks = i * 8 + part;
    const float4 a = sp[ks * 2], b = sp[ks * 2 + 1];
    f16x8 vv;
    vv[0] = (_Float16)a.x; vv[1] = (_Float16)a.y; vv[2] = (_Float16)a.z; vv[3] = (_Float16)a.w;
    vv[4] = (_Float16)b.x; vv[5] = (_Float16)b.y; vv[6] = (_Float16)b.z; vv[7] = (_Float16)b.w;
    *(f16x8*)(A + ((size_t)ks * 65 + row) * 8) = vv;
  }
}

// 24 blocks: stage s = bid>>3 (layer), slice c = bid&7 (64 output cols).
// 8 waves = 2(M) x 4(N): wave computes M=32 rows x N=16 cols, weights VGPR-resident.
__global__ __launch_bounds__(512, 2) void rnn6_kernel(
    const float* __restrict__ inputs, const _Float16* __restrict__ v_all,
    const int use_v, const _Float16* __restrict__ packB,
    const float* __restrict__ bfold, const float* __restrict__ csum,
    _Float16* __restrict__ h_ex, unsigned* __restrict__ arr,
    unsigned* __restrict__ cons)
{
  const int bid = blockIdx.x;
  const int s = bid >> 3, c = bid & 7;
  const int tid = threadIdx.x;
  const int l = tid & 63, w = tid >> 6;
  const int mg = w >> 2, ng = w & 3;     // 2 x 4 wave grid

  __shared__ __align__(16) _Float16 A1[ATILE_HALVES];
  __shared__ __align__(16) _Float16 A2[ATILE_HALVES];
  __shared__ __align__(16) _Float16 hout[64][72];
  __shared__ float muS[64], rsS[64];

  const bool sx = (s == 0);
  const bool havev = (use_v != 0);
  const bool needX = (!sx || !havev);

  // ---- one-time register-resident B slices (16 col set per wave)
  const int colbase = c * 64 + ng * 16 + (l & 15);
  const int kbase = (l >> 4) * 8;
  f16x8 Bx[16], Bh[16];
  {
    const _Float16* ph = packB + ((size_t)(s * 2 + 1) * DH + colbase) * DH + kbase;
#pragma unroll
    for (int kk = 0; kk < 16; ++kk) Bh[kk] = *(const f16x8*)(ph + kk * 32);
  }
  if (needX) {
    const _Float16* px = packB + ((size_t)(s * 2 + 0) * DH + colbase) * DH + kbase;
#pragma unroll
    for (int kk = 0; kk < 16; ++kk) Bx[kk] = *(const f16x8*)(px + kk * 32);
  }

  const float b_j = bfold[s * DH + colbase];
  const float cs_j = (s > 0) ? csum[(s - 1) * DH + colbase] : 0.f;

  // zero A2 (h_prev = 0 at t=0)
  {
    f16x8 z;
#pragma unroll
    for (int e = 0; e < 8; ++e) z[e] = (_Float16)0.f;
#pragma unroll
    for (int q = 0; q < 9; ++q) {
      const int gidx = q * 512 + tid;
      if (gidx < 64 * 65) *(f16x8*)(A2 + (size_t)gidx * 8) = z;
    }
  }

  for (int t = 0; t < TT; ++t) {
    // ---- poll flags: wave 0, relaxed loads only (no cache maintenance)
    if (w == 0) {
      const int li = l & 7, grp = l >> 3;
      unsigned* p = nullptr; unsigned tgt = 0;
      if (grp == 0 && t >= 1)                   { p = arr  + (s * 8 + li) * 16;        tgt = (unsigned)t; }
      else if (grp == 1 && s > 0)               { p = arr  + ((s - 1) * 8 + li) * 16;  tgt = (unsigned)(t + 1); }
      else if (grp == 2 && s < 2 && t >= RD)    { p = cons + (s * 8 + li) * 16;        tgt = (unsigned)(t - RD + 1); }
      while (true) {
        bool mine = true;
        if (p) mine = (__hip_atomic_load(p, __ATOMIC_RELAXED, __HIP_MEMORY_SCOPE_AGENT) >= tgt);
        if (__all(mine)) break;
        __builtin_amdgcn_s_sleep(2);
      }
    }
    __syncthreads();   // data is read via coherent (volatile sc0sc1) loads -> no fence

    // ---- stage operands (volatile loads bypass stale L2, hit LLC)
    if (t >= 1)
      stage_hv(A2, h_ex + (size_t)(s * RD + ((t - 1) & (RD - 1))) * BB * DH,
               nullptr, nullptr, false, tid);
    if (!sx)
      stage_hv(A1, h_ex + (size_t)((s - 1) * RD + (t & (RD - 1))) * BB * DH,
               muS, rsS, true, tid);
    else if (!havev)
      stage_x(A1, inputs, t, tid);
    __syncthreads();
    if (tid == 0 && s > 0)
      __hip_atomic_store(cons + ((s - 1) * 8 + c) * 16, (unsigned)(t + 1),
                         __ATOMIC_RELAXED, __HIP_MEMORY_SCOPE_AGENT);

    // ---- GEMM (K = 512): wave does M=32 (mf 0..1) x N=16
    f32x4 accX[2], accH[2];
#pragma unroll
    for (int mf = 0; mf < 2; ++mf)
#pragma unroll
      for (int e = 0; e < 4; ++e) { accX[mf][e] = 0.f; accH[mf][e] = 0.f; }
    const int g = l >> 4;
#pragma unroll
    for (int kk = 0; kk < 16; ++kk) {
      const int ks = kk * 4 + g;
#pragma unroll
      for (int mf = 0; mf < 2; ++mf) {
        const int arow = mg * 32 + mf * 16 + (l & 15);
        const f16x8 aH = *(const f16x8*)(A2 + ((size_t)ks * 65 + arow) * 8);
        accH[mf] = __builtin_amdgcn_mfma_f32_16x16x32_f16(aH, Bh[kk], accH[mf], 0, 0, 0);
        if (needX) {
          const f16x8 aX = *(const f16x8*)(A1 + ((size_t)ks * 65 + arow) * 8);
          accX[mf] = __builtin_amdgcn_mfma_f32_16x16x32_f16(aX, Bx[kk], accX[mf], 0, 0, 0);
        }
      }
    }

    // ---- epilogue -> hout (LDS), then coalesced coherent writeback
    const int jl = ng * 16 + (l & 15);
#pragma unroll
    for (int mf = 0; mf < 2; ++mf)
#pragma unroll
      for (int i = 0; i < 4; ++i) {
        const int r = mg * 32 + mf * 16 + (l >> 4) * 4 + i;
        float p;
        if (sx) {
          float v0;
          if (havev) v0 = (float)v_all[((size_t)t * BB + r) * DH + c * 64 + jl];
          else       v0 = accX[mf][i];
          p = v0 + accH[mf][i] + b_j;
        } else {
          p = rsS[r] * (accX[mf][i] - muS[r] * cs_j) + accH[mf][i] + b_j;
        }
        hout[r][jl] = (_Float16)tanhf(p);
      }
    __syncthreads();
    {
      _Float16* dst = h_ex + (size_t)(s * RD + (t & (RD - 1))) * BB * DH;
      const int row = tid >> 3, ch = tid & 7;
      const f16x8 hv = *(const f16x8*)(&hout[row][ch * 8]);
      cstore(dst + (size_t)row * DH + c * 64 + ch * 8, hv);
    }
    __syncthreads();   // drains vmcnt: coherent stores visible at LLC
    if (tid == 0)
      __hip_atomic_store(arr + (s * 8 + c) * 16, (unsigned)(t + 1),
                         __ATOMIC_RELAXED, __HIP_MEMORY_SCOPE_AGENT);
  }
}

// ---------------------------------------------------------------- classifier

__global__ __launch_bounds__(64) void clf_kernel(
    const _Float16* __restrict__ h2, const float* __restrict__ clfwf,
    const float* __restrict__ clfbf, float* __restrict__ out)
{
  const int b = blockIdx.x, d = threadIdx.x;
  __shared__ float o2[DH];
  const _Float16* hrow = h2 + (size_t)b * DH;
  float sum = 0.f, sq = 0.f;
#pragma unroll
  for (int i = 0; i < 8; ++i) {
    const float v = (float)hrow[d * 8 + i];
    sum += v; sq += v * v;
  }
#pragma unroll
  for (int off = 32; off; off >>= 1) { sum += __shfl_xor(sum, off); sq += __shfl_xor(sq, off); }
  const float mu = sum * (1.f / DH);
  const float rs = rsqrtf(sq * (1.f / DH) - mu * mu + 1e-5f);
#pragma unroll
  for (int i = 0; i < 8; ++i) o2[d * 8 + i] = ((float)hrow[d * 8 + i] - mu) * rs;
  __syncthreads();
  float acc = clfbf[d];
#pragma unroll 8
  for (int k = 0; k < DH; ++k) acc = fmaf(o2[k], clfwf[k * DT + d], acc);
  float mx = acc;
#pragma unroll
  for (int off = 32; off; off >>= 1) mx = fmaxf(mx, __shfl_xor(mx, off));
  const float e = expf(acc - mx);
  float ss = e;
#pragma unroll
  for (int off = 32; off; off >>= 1) ss += __shfl_xor(ss, off);
  out[(size_t)b * DT + d] = e / ss;
}

// ---------------------------------------------------------------- launch

extern "C" void kernel_launch(void* const* d_in, const int* in_sizes, int n_in,
                              void* d_out, int out_size, void* d_ws, size_t ws_size,
                              hipStream_t stream) {
  const float* inputs = (const float*)d_in[0];
  const float* emb    = (const float*)d_in[1];
  const float* wx0    = (const float*)d_in[2];
  const float* wh0    = (const float*)d_in[3];
  const float* b0     = (const float*)d_in[4];
  const float* wx1    = (const float*)d_in[5];
  const float* wh1    = (const float*)d_in[6];
  const float* b1     = (const float*)d_in[7];
  const float* wx2    = (const float*)d_in[8];
  const float* wh2    = (const float*)d_in[9];
  const float* b2     = (const float*)d_in[10];
  const float* gamma  = (const float*)d_in[11];
  const float* beta   = (const float*)d_in[12];
  const float* clfw   = (const float*)d_in[13];
  const float* clfb   = (const float*)d_in[14];
  float* out = (float*)d_out;

  char* ws = (char*)d_ws;
  size_t off = 0;
  float*    Ep    = (float*)(ws + off);    off += (size_t)DH * DH * 4;               // 1 MB
  _Float16* packB = (_Float16*)(ws + off); off += (size_t)6 * DH * DH * 2;           // 3 MB
  _Float16* h_ex  = (_Float16*)(ws + off); off += (size_t)3 * RD * BB * DH * 2;      // 768 KB
  float*    bfold = (float*)(ws + off);    off += (size_t)3 * DH * 4;
  float*    csumP = (float*)(ws + off);    off += (size_t)2 * DH * 4;
  float*    clfwf = (float*)(ws + off);    off += (size_t)DH * DT * 4;               // 128 KB
  float*    clfbf = (float*)(ws + off);    off += 256;
  unsigned* arr   = (unsigned*)(ws + off); off += (size_t)3 * 8 * 16 * 4;            // 1.5 KB
  unsigned* cons  = (unsigned*)(ws + off); off += (size_t)2 * 8 * 16 * 4;            // 1 KB
  off = (off + 255) & ~(size_t)255;
  _Float16* v_all = (_Float16*)(ws + off);
  const size_t need_v = off + (size_t)TT * BB * DH * 2;                              // +64 MB
  const int use_v = (ws_size >= need_v) ? 1 : 0;

  (void)hipMemsetAsync(arr, 0, (size_t)(3 * 8 * 16 + 2 * 8 * 16) * 4, stream);
  hipLaunchKernelGGL(eprime_kernel, dim3(DH), dim3(512), 0, stream, emb, wx0, Ep);
  hipLaunchKernelGGL(pack_kernel, dim3(8, 8, 6), dim3(512), 0, stream,
                     Ep, wh0, wx1, wh1, wx2, wh2, gamma, packB);
  hipLaunchKernelGGL(fold_kernel, dim3(2), dim3(512), 0, stream,
                     b0, b1, b2, wx1, wx2, gamma, beta, clfw, clfb,
                     bfold, csumP, clfwf, clfbf);
  if (use_v)
    hipLaunchKernelGGL(vgemm_kernel, dim3(TT), dim3(512), 0, stream,
                       inputs, packB, v_all);
  hipLaunchKernelGGL(rnn6_kernel, dim3(24), dim3(512), 0, stream,
                     inputs, v_all, use_v, packB, bfold, csumP, h_ex, arr, cons);
  // final h2 lives in slot (1023 & (RD-1)) = 3 of stage 2
  const _Float16* h2fin = h_ex + (size_t)(2 * RD + ((TT - 1) & (RD - 1))) * BB * DH;
  hipLaunchKernelGGL(clf_kernel, dim3(BB), dim3(DT), 0, stream,
                     h2fin, clfwf, clfbf, out);
}

// Round 7
// 10286.996 us; speedup vs baseline: 8.7099x; 1.0010x over previous
//
#include <hip/hip_runtime.h>

#define DH 512
#define TT 1024
#define BB 64
#define DT 64
#define RD 4  // h_ex ring depth

typedef _Float16 f16x8 __attribute__((ext_vector_type(8)));
typedef float f32x4 __attribute__((ext_vector_type(4)));

// LDS A-tile subtile layout: element (row r, k) at A[((k>>3)*65 + r)*8 + (k&7)]
#define ATILE_HALVES (64 * 65 * 8)

// Coherent (LLC-level, sc0 sc1) accesses via volatile — bypass non-coherent L2.
__device__ __forceinline__ f16x8 cload(const _Float16* p) {
  return *(const volatile f16x8*)p;
}
__device__ __forceinline__ void cstore(_Float16* p, f16x8 v) {
  *(volatile f16x8*)p = v;
}

// ---------------------------------------------------------------- precompute

__global__ __launch_bounds__(512) void eprime_kernel(
    const float* __restrict__ emb, const float* __restrict__ wx0,
    float* __restrict__ Ep)
{
  __shared__ float er[DH];
  const int e = blockIdx.x, j = threadIdx.x;
  er[j] = emb[(size_t)e * DH + j];
  __syncthreads();
  float acc = 0.f;
#pragma unroll 8
  for (int k = 0; k < DH; ++k) acc = fmaf(er[k], wx0[(size_t)k * DH + j], acc);
  Ep[(size_t)e * DH + j] = acc;
}

// packB[m][j][k] = fold_m[k] * src_m[k][j]  (fp16 col-major)
__global__ __launch_bounds__(512) void pack_kernel(
    const float* __restrict__ Ep, const float* __restrict__ wh0,
    const float* __restrict__ wx1, const float* __restrict__ wh1,
    const float* __restrict__ wx2, const float* __restrict__ wh2,
    const float* __restrict__ gamma, _Float16* __restrict__ dst)
{
  __shared__ float Tt[64][65];
  const int m = blockIdx.z, jt = blockIdx.x, kt = blockIdx.y;
  const float* src = (m == 0) ? Ep : (m == 1) ? wh0 : (m == 2) ? wx1
                   : (m == 3) ? wh1 : (m == 4) ? wx2 : wh2;
  const bool fold = (m == 2 || m == 4);
  const int tx = threadIdx.x & 63, ty = threadIdx.x >> 6;
#pragma unroll
  for (int i = 0; i < 8; ++i) {
    const int k = kt * 64 + ty * 8 + i;
    Tt[ty * 8 + i][tx] = src[(size_t)k * DH + jt * 64 + tx];
  }
  __syncthreads();
#pragma unroll
  for (int i = 0; i < 8; ++i) {
    const int j = jt * 64 + ty * 8 + i;
    const int k = kt * 64 + tx;
    float v = Tt[tx][ty * 8 + i];
    if (fold) v *= gamma[k];
    dst[((size_t)m * DH + j) * DH + k] = (_Float16)v;
  }
}

__global__ __launch_bounds__(512) void fold_kernel(
    const float* __restrict__ b0, const float* __restrict__ b1,
    const float* __restrict__ b2, const float* __restrict__ wx1,
    const float* __restrict__ wx2, const float* __restrict__ gamma,
    const float* __restrict__ beta, const float* __restrict__ clfw,
    const float* __restrict__ clfb,
    float* __restrict__ bfold, float* __restrict__ csum,
    float* __restrict__ clfwf, float* __restrict__ clfbf)
{
  const int j = threadIdx.x;
  if (blockIdx.x == 0) {
    bfold[j] = b0[j];
    float s1 = 0, s2 = 0, c1 = 0, c2 = 0;
    for (int k = 0; k < DH; ++k) {
      const float w1 = wx1[(size_t)k * DH + j], w2 = wx2[(size_t)k * DH + j];
      s1 += beta[k] * w1;  s2 += beta[k] * w2;
      c1 += gamma[k] * w1; c2 += gamma[k] * w2;
    }
    bfold[DH + j] = b1[j] + s1;
    bfold[2 * DH + j] = b2[j] + s2;
    csum[j] = c1; csum[DH + j] = c2;
  } else {
    for (int idx = j; idx < DH * DT; idx += 512) {
      const int k = idx >> 6, d = idx & 63;
      clfwf[idx] = gamma[k] * clfw[(size_t)k * DT + d];
    }
    if (j < DT) {
      float sb = clfb[j];
      for (int k = 0; k < DH; ++k) sb += beta[k] * clfw[(size_t)k * DT + j];
      clfbf[j] = sb;
    }
  }
}

// v_all[t][b][j] (fp16) = sum_e x[b][t][e] * E'[e][j];  one block per t.
__global__ __launch_bounds__(512, 1) void vgemm_kernel(
    const float* __restrict__ x, const _Float16* __restrict__ Bt,
    _Float16* __restrict__ v)
{
  const int t = blockIdx.x;
  const int tid = threadIdx.x, l = tid & 63, w = tid >> 6;
  __shared__ __align__(16) _Float16 A[ATILE_HALVES];
  {
    const int row = tid >> 3, part = tid & 7;
    const float4* sp = (const float4*)(x + ((size_t)row * TT + t) * DH);
#pragma unroll
    for (int i = 0; i < 8; ++i) {
      const int ks = i * 8 + part;
      const float4 a = sp[ks * 2], b = sp[ks * 2 + 1];
      f16x8 vv;
      vv[0] = (_Float16)a.x; vv[1] = (_Float16)a.y; vv[2] = (_Float16)a.z; vv[3] = (_Float16)a.w;
      vv[4] = (_Float16)b.x; vv[5] = (_Float16)b.y; vv[6] = (_Float16)b.z; vv[7] = (_Float16)b.w;
      *(f16x8*)(A + ((size_t)ks * 65 + row) * 8) = vv;
    }
  }
  __syncthreads();
  const int jb = w * 64;
  const int arowb = l & 15, g = l >> 4;
  f32x4 acc[4][4];
#pragma unroll
  for (int mf = 0; mf < 4; ++mf)
#pragma unroll
    for (int nf = 0; nf < 4; ++nf)
#pragma unroll
      for (int e = 0; e < 4; ++e) acc[mf][nf][e] = 0.f;
#pragma unroll
  for (int kk = 0; kk < 16; ++kk) {
    const int ks = kk * 4 + g;
    f16x8 am[4], bn[4];
#pragma unroll
    for (int mf = 0; mf < 4; ++mf)
      am[mf] = *(const f16x8*)(A + ((size_t)ks * 65 + mf * 16 + arowb) * 8);
#pragma unroll
    for (int nf = 0; nf < 4; ++nf)
      bn[nf] = *(const f16x8*)(Bt + (size_t)(jb + nf * 16 + arowb) * DH + kk * 32 + g * 8);
#pragma unroll
    for (int mf = 0; mf < 4; ++mf)
#pragma unroll
      for (int nf = 0; nf < 4; ++nf)
        acc[mf][nf] = __builtin_amdgcn_mfma_f32_16x16x32_f16(am[mf], bn[nf], acc[mf][nf], 0, 0, 0);
  }
#pragma unroll
  for (int mf = 0; mf < 4; ++mf)
#pragma unroll
    for (int nf = 0; nf < 4; ++nf)
#pragma unroll
      for (int i = 0; i < 4; ++i) {
        const int r = mf * 16 + (l >> 4) * 4 + i;
        const int j = jb + nf * 16 + (l & 15);
        v[((size_t)t * BB + r) * DH + j] = (_Float16)acc[mf][nf][i];
      }
}

// ---------------------------------------------------------------- main RNN

// Coherent-stage [64x512] fp16 (LLC) -> LDS, optional row stats.
__device__ __forceinline__ void stage_hv(_Float16* __restrict__ A,
                                         const _Float16* __restrict__ src,
                                         float* muA, float* rsA, bool stats,
                                         int tid)
{
  const int row = tid >> 3, part = tid & 7;
  const _Float16* sp = src + (size_t)row * DH;
  f16x8 v[8];
#pragma unroll
  for (int i = 0; i < 8; ++i) v[i] = cload(sp + (size_t)(i * 8 + part) * 8);
  float sum = 0.f, sq = 0.f;
#pragma unroll
  for (int i = 0; i < 8; ++i) {
    const int ks = i * 8 + part;
    *(f16x8*)(A + ((size_t)ks * 65 + row) * 8) = v[i];
    if (stats) {
#pragma unroll
      for (int e = 0; e < 8; ++e) { const float f = (float)v[i][e]; sum += f; sq += f * f; }
    }
  }
  if (stats) {
    sum += __shfl_xor(sum, 1); sq += __shfl_xor(sq, 1);
    sum += __shfl_xor(sum, 2); sq += __shfl_xor(sq, 2);
    sum += __shfl_xor(sum, 4); sq += __shfl_xor(sq, 4);
    if (part == 0) {
      const float mu = sum * (1.f / DH);
      const float var = sq * (1.f / DH) - mu * mu;
      muA[row] = mu; rsA[row] = rsqrtf(var + 1e-5f);
    }
  }
}

__device__ __forceinline__ void stage_x(_Float16* __restrict__ A,
                                        const float* __restrict__ inputs,
                                        int t, int tid)
{
  const int row = tid >> 3, part = tid & 7;
  const float4* sp = (const float4*)(inputs + ((size_t)row * TT + t) * DH);
#pragma unroll
  for (int i = 0; i < 8; ++i) {
    const int ks = i * 8 + part;
    const float4 a = sp[ks * 2], b = sp[ks * 2 + 1];
    f16x8 vv;
    vv[0] = (_Float16)a.x; vv[1] = (_Float16)a.y; vv[2] = (_Float16)a.z; vv[3] = (_Float16)a.w;
    vv[4] = (_Float16)b.x; vv[5] = (_Float16)b.y; vv[6] = (_Float16)b.z; vv[7] = (_Float16)b.w;
    *(f16x8*)(A + ((size_t)ks * 65 + row) * 8) = vv;
  }
}

// 24 blocks: stage s = bid>>3 (layer), slice c = bid&7 (64 output cols).
// 8 waves = 2(M) x 4(N): wave computes M=32 rows x N=16 cols, weights VGPR-resident.
// launch_bounds(512, 1): allow up to 256 VGPR/thread (8 waves/CU still fit).
__global__ __launch_bounds__(512, 1) void rnn7_kernel(
    const float* __restrict__ inputs, const _Float16* __restrict__ v_all,
    const int use_v, const _Float16* __restrict__ packB,
    const float* __restrict__ bfold, const float* __restrict__ csum,
    _Float16* __restrict__ h_ex, unsigned* __restrict__ arr,
    unsigned* __restrict__ cons)
{
  const int bid = blockIdx.x;
  const int s = bid >> 3, c = bid & 7;
  const int tid = threadIdx.x;
  const int l = tid & 63, w = tid >> 6;
  const int mg = w >> 2, ng = w & 3;     // 2 x 4 wave grid

  __shared__ __align__(16) _Float16 A1[ATILE_HALVES];
  __shared__ __align__(16) _Float16 A2[ATILE_HALVES];
  __shared__ __align__(16) _Float16 hout[64][72];
  __shared__ float muS[64], rsS[64];

  const bool sx = (s == 0);
  const bool havev = (use_v != 0);
  const bool needX = (!sx || !havev);

  // ---- one-time register-resident B slices (16 col set per wave)
  const int colbase = c * 64 + ng * 16 + (l & 15);
  const int kbase = (l >> 4) * 8;
  f16x8 Bx[16], Bh[16];
  {
    const _Float16* ph = packB + ((size_t)(s * 2 + 1) * DH + colbase) * DH + kbase;
#pragma unroll
    for (int kk = 0; kk < 16; ++kk) Bh[kk] = *(const f16x8*)(ph + kk * 32);
  }
  if (needX) {
    const _Float16* px = packB + ((size_t)(s * 2 + 0) * DH + colbase) * DH + kbase;
#pragma unroll
    for (int kk = 0; kk < 16; ++kk) Bx[kk] = *(const f16x8*)(px + kk * 32);
  }

  const float b_j = bfold[s * DH + colbase];
  const float cs_j = (s > 0) ? csum[(s - 1) * DH + colbase] : 0.f;

  // zero A2 (h_prev = 0 at t=0)
  {
    f16x8 z;
#pragma unroll
    for (int e = 0; e < 8; ++e) z[e] = (_Float16)0.f;
#pragma unroll
    for (int q = 0; q < 9; ++q) {
      const int gidx = q * 512 + tid;
      if (gidx < 64 * 65) *(f16x8*)(A2 + (size_t)gidx * 8) = z;
    }
  }

  for (int t = 0; t < TT; ++t) {
    // ---- poll flags: wave 0, relaxed loads only (no cache maintenance)
    if (w == 0) {
      const int li = l & 7, grp = l >> 3;
      unsigned* p = nullptr; unsigned tgt = 0;
      if (grp == 0 && t >= 1)                   { p = arr  + (s * 8 + li) * 16;        tgt = (unsigned)t; }
      else if (grp == 1 && s > 0)               { p = arr  + ((s - 1) * 8 + li) * 16;  tgt = (unsigned)(t + 1); }
      else if (grp == 2 && s < 2 && t >= RD)    { p = cons + (s * 8 + li) * 16;        tgt = (unsigned)(t - RD + 1); }
      while (true) {
        bool mine = true;
        if (p) mine = (__hip_atomic_load(p, __ATOMIC_RELAXED, __HIP_MEMORY_SCOPE_AGENT) >= tgt);
        if (__all(mine)) break;
        __builtin_amdgcn_s_sleep(2);
      }
    }
    __syncthreads();   // data is read via coherent (volatile sc0sc1) loads -> no fence

    // ---- stage operands (volatile loads bypass stale L2, hit LLC)
    if (t >= 1)
      stage_hv(A2, h_ex + (size_t)(s * RD + ((t - 1) & (RD - 1))) * BB * DH,
               nullptr, nullptr, false, tid);
    if (!sx)
      stage_hv(A1, h_ex + (size_t)((s - 1) * RD + (t & (RD - 1))) * BB * DH,
               muS, rsS, true, tid);
    else if (!havev)
      stage_x(A1, inputs, t, tid);
    __syncthreads();
    if (tid == 0 && s > 0)
      __hip_atomic_store(cons + ((s - 1) * 8 + c) * 16, (unsigned)(t + 1),
                         __ATOMIC_RELAXED, __HIP_MEMORY_SCOPE_AGENT);

    // ---- GEMM (K = 512): wave does M=32 (mf 0..1) x N=16
    f32x4 accX[2], accH[2];
#pragma unroll
    for (int mf = 0; mf < 2; ++mf)
#pragma unroll
      for (int e = 0; e < 4; ++e) { accX[mf][e] = 0.f; accH[mf][e] = 0.f; }
    const int g = l >> 4;
#pragma unroll
    for (int kk = 0; kk < 16; ++kk) {
      const int ks = kk * 4 + g;
#pragma unroll
      for (int mf = 0; mf < 2; ++mf) {
        const int arow = mg * 32 + mf * 16 + (l & 15);
        const f16x8 aH = *(const f16x8*)(A2 + ((size_t)ks * 65 + arow) * 8);
        accH[mf] = __builtin_amdgcn_mfma_f32_16x16x32_f16(aH, Bh[kk], accH[mf], 0, 0, 0);
        if (needX) {
          const f16x8 aX = *(const f16x8*)(A1 + ((size_t)ks * 65 + arow) * 8);
          accX[mf] = __builtin_amdgcn_mfma_f32_16x16x32_f16(aX, Bx[kk], accX[mf], 0, 0, 0);
        }
      }
    }

    // ---- epilogue -> hout (LDS), then coalesced coherent writeback
    const int jl = ng * 16 + (l & 15);
#pragma unroll
    for (int mf = 0; mf < 2; ++mf)
#pragma unroll
      for (int i = 0; i < 4; ++i) {
        const int r = mg * 32 + mf * 16 + (l >> 4) * 4 + i;
        float p;
        if (sx) {
          float v0;
          if (havev) v0 = (float)v_all[((size_t)t * BB + r) * DH + c * 64 + jl];
          else       v0 = accX[mf][i];
          p = v0 + accH[mf][i] + b_j;
        } else {
          p = rsS[r] * (accX[mf][i] - muS[r] * cs_j) + accH[mf][i] + b_j;
        }
        hout[r][jl] = (_Float16)tanhf(p);
      }
    __syncthreads();
    {
      _Float16* dst = h_ex + (size_t)(s * RD + (t & (RD - 1))) * BB * DH;
      const int row = tid >> 3, ch = tid & 7;
      const f16x8 hv = *(const f16x8*)(&hout[row][ch * 8]);
      cstore(dst + (size_t)row * DH + c * 64 + ch * 8, hv);
    }
    __syncthreads();   // drains vmcnt: coherent stores visible at LLC
    if (tid == 0)
      __hip_atomic_store(arr + (s * 8 + c) * 16, (unsigned)(t + 1),
                         __ATOMIC_RELAXED, __HIP_MEMORY_SCOPE_AGENT);
  }
}

// ---------------------------------------------------------------- classifier

__global__ __launch_bounds__(64) void clf_kernel(
    const _Float16* __restrict__ h2, const float* __restrict__ clfwf,
    const float* __restrict__ clfbf, float* __restrict__ out)
{
  const int b = blockIdx.x, d = threadIdx.x;
  __shared__ float o2[DH];
  const _Float16* hrow = h2 + (size_t)b * DH;
  float sum = 0.f, sq = 0.f;
#pragma unroll
  for (int i = 0; i < 8; ++i) {
    const float v = (float)hrow[d * 8 + i];
    sum += v; sq += v * v;
  }
#pragma unroll
  for (int off = 32; off; off >>= 1) { sum += __shfl_xor(sum, off); sq += __shfl_xor(sq, off); }
  const float mu = sum * (1.f / DH);
  const float rs = rsqrtf(sq * (1.f / DH) - mu * mu + 1e-5f);
#pragma unroll
  for (int i = 0; i < 8; ++i) o2[d * 8 + i] = ((float)hrow[d * 8 + i] - mu) * rs;
  __syncthreads();
  float acc = clfbf[d];
#pragma unroll 8
  for (int k = 0; k < DH; ++k) acc = fmaf(o2[k], clfwf[k * DT + d], acc);
  float mx = acc;
#pragma unroll
  for (int off = 32; off; off >>= 1) mx = fmaxf(mx, __shfl_xor(mx, off));
  const float e = expf(acc - mx);
  float ss = e;
#pragma unroll
  for (int off = 32; off; off >>= 1) ss += __shfl_xor(ss, off);
  out[(size_t)b * DT + d] = e / ss;
}

// ---------------------------------------------------------------- launch

extern "C" void kernel_launch(void* const* d_in, const int* in_sizes, int n_in,
                              void* d_out, int out_size, void* d_ws, size_t ws_size,
                              hipStream_t stream) {
  const float* inputs = (const float*)d_in[0];
  const float* emb    = (const float*)d_in[1];
  const float* wx0    = (const float*)d_in[2];
  const float* wh0    = (const float*)d_in[3];
  const float* b0     = (const float*)d_in[4];
  const float* wx1    = (const float*)d_in[5];
  const float* wh1    = (const float*)d_in[6];
  const float* b1     = (const float*)d_in[7];
  const float* wx2    = (const float*)d_in[8];
  const float* wh2    = (const float*)d_in[9];
  const float* b2     = (const float*)d_in[10];
  const float* gamma  = (const float*)d_in[11];
  const float* beta   = (const float*)d_in[12];
  const float* clfw   = (const float*)d_in[13];
  const float* clfb   = (const float*)d_in[14];
  float* out = (float*)d_out;

  char* ws = (char*)d_ws;
  size_t off = 0;
  float*    Ep    = (float*)(ws + off);    off += (size_t)DH * DH * 4;               // 1 MB
  _Float16* packB = (_Float16*)(ws + off); off += (size_t)6 * DH * DH * 2;           // 3 MB
  _Float16* h_ex  = (_Float16*)(ws + off); off += (size_t)3 * RD * BB * DH * 2;      // 768 KB
  float*    bfold = (float*)(ws + off);    off += (size_t)3 * DH * 4;
  float*    csumP = (float*)(ws + off);    off += (size_t)2 * DH * 4;
  float*    clfwf = (float*)(ws + off);    off += (size_t)DH * DT * 4;               // 128 KB
  float*    clfbf = (float*)(ws + off);    off += 256;
  unsigned* arr   = (unsigned*)(ws + off); off += (size_t)3 * 8 * 16 * 4;            // 1.5 KB
  unsigned* cons  = (unsigned*)(ws + off); off += (size_t)2 * 8 * 16 * 4;            // 1 KB
  off = (off + 255) & ~(size_t)255;
  _Float16* v_all = (_Float16*)(ws + off);
  const size_t need_v = off + (size_t)TT * BB * DH * 2;                              // +64 MB
  const int use_v = (ws_size >= need_v) ? 1 : 0;

  (void)hipMemsetAsync(arr, 0, (size_t)(3 * 8 * 16 + 2 * 8 * 16) * 4, stream);
  hipLaunchKernelGGL(eprime_kernel, dim3(DH), dim3(512), 0, stream, emb, wx0, Ep);
  hipLaunchKernelGGL(pack_kernel, dim3(8, 8, 6), dim3(512), 0, stream,
                     Ep, wh0, wx1, wh1, wx2, wh2, gamma, packB);
  hipLaunchKernelGGL(fold_kernel, dim3(2), dim3(512), 0, stream,
                     b0, b1, b2, wx1, wx2, gamma, beta, clfw, clfb,
                     bfold, csumP, clfwf, clfbf);
  if (use_v)
    hipLaunchKernelGGL(vgemm_kernel, dim3(TT), dim3(512), 0, stream,
                       inputs, packB, v_all);
  hipLaunchKernelGGL(rnn7_kernel, dim3(24), dim3(512), 0, stream,
                     inputs, v_all, use_v, packB, bfold, csumP, h_ex, arr, cons);
  // final h2 lives in slot (1023 & (RD-1)) = 3 of stage 2
  const _Float16* h2fin = h_ex + (size_t)(2 * RD + ((TT - 1) & (RD - 1))) * BB * DH;
  hipLaunchKernelGGL(clf_kernel, dim3(BB), dim3(DT), 0, stream,
                     h2fin, clfwf, clfbf, out);
}

// Round 8
// 7485.217 us; speedup vs baseline: 11.9701x; 1.3743x over previous
//
#include <hip/hip_runtime.h>

#define DH 512
#define TT 1024
#define BB 64
#define DT 64
#define RD 4  // ring depth (fallback mode only)

typedef _Float16 f16x8 __attribute__((ext_vector_type(8)));
typedef float f32x4 __attribute__((ext_vector_type(4)));

// LDS A-tile subtile layout: element (row r, k) at A[((k>>3)*65 + r)*8 + (k&7)]
#define ATILE_HALVES (64 * 65 * 8)

// Coherent (LLC-level, sc0 sc1) accesses via volatile — bypass non-coherent L2.
__device__ __forceinline__ f16x8 cload(const _Float16* p) {
  return *(const volatile f16x8*)p;
}
__device__ __forceinline__ void cstore(_Float16* p, f16x8 v) {
  *(volatile f16x8*)p = v;
}

// ---------------------------------------------------------------- precompute

__global__ __launch_bounds__(512) void eprime_kernel(
    const float* __restrict__ emb, const float* __restrict__ wx0,
    float* __restrict__ Ep)
{
  __shared__ float er[DH];
  const int e = blockIdx.x, j = threadIdx.x;
  er[j] = emb[(size_t)e * DH + j];
  __syncthreads();
  float acc = 0.f;
#pragma unroll 8
  for (int k = 0; k < DH; ++k) acc = fmaf(er[k], wx0[(size_t)k * DH + j], acc);
  Ep[(size_t)e * DH + j] = acc;
}

// packB[m][j][k] = fold_m[k] * src_m[k][j]  (fp16 col-major)
__global__ __launch_bounds__(512) void pack_kernel(
    const float* __restrict__ Ep, const float* __restrict__ wh0,
    const float* __restrict__ wx1, const float* __restrict__ wh1,
    const float* __restrict__ wx2, const float* __restrict__ wh2,
    const float* __restrict__ gamma, _Float16* __restrict__ dst)
{
  __shared__ float Tt[64][65];
  const int m = blockIdx.z, jt = blockIdx.x, kt = blockIdx.y;
  const float* src = (m == 0) ? Ep : (m == 1) ? wh0 : (m == 2) ? wx1
                   : (m == 3) ? wh1 : (m == 4) ? wx2 : wh2;
  const bool fold = (m == 2 || m == 4);
  const int tx = threadIdx.x & 63, ty = threadIdx.x >> 6;
#pragma unroll
  for (int i = 0; i < 8; ++i) {
    const int k = kt * 64 + ty * 8 + i;
    Tt[ty * 8 + i][tx] = src[(size_t)k * DH + jt * 64 + tx];
  }
  __syncthreads();
#pragma unroll
  for (int i = 0; i < 8; ++i) {
    const int j = jt * 64 + ty * 8 + i;
    const int k = kt * 64 + tx;
    float v = Tt[tx][ty * 8 + i];
    if (fold) v *= gamma[k];
    dst[((size_t)m * DH + j) * DH + k] = (_Float16)v;
  }
}

__global__ __launch_bounds__(512) void fold_kernel(
    const float* __restrict__ b0, const float* __restrict__ b1,
    const float* __restrict__ b2, const float* __restrict__ wx1,
    const float* __restrict__ wx2, const float* __restrict__ gamma,
    const float* __restrict__ beta, const float* __restrict__ clfw,
    const float* __restrict__ clfb,
    float* __restrict__ bfold, float* __restrict__ csum,
    float* __restrict__ clfwf, float* __restrict__ clfbf)
{
  const int j = threadIdx.x;
  if (blockIdx.x == 0) {
    bfold[j] = b0[j];
    float s1 = 0, s2 = 0, c1 = 0, c2 = 0;
    for (int k = 0; k < DH; ++k) {
      const float w1 = wx1[(size_t)k * DH + j], w2 = wx2[(size_t)k * DH + j];
      s1 += beta[k] * w1;  s2 += beta[k] * w2;
      c1 += gamma[k] * w1; c2 += gamma[k] * w2;
    }
    bfold[DH + j] = b1[j] + s1;
    bfold[2 * DH + j] = b2[j] + s2;
    csum[j] = c1; csum[DH + j] = c2;
  } else {
    for (int idx = j; idx < DH * DT; idx += 512) {
      const int k = idx >> 6, d = idx & 63;
      clfwf[idx] = gamma[k] * clfw[(size_t)k * DT + d];
    }
    if (j < DT) {
      float sb = clfb[j];
      for (int k = 0; k < DH; ++k) sb += beta[k] * clfw[(size_t)k * DT + j];
      clfbf[j] = sb;
    }
  }
}

// v_all[t][b][j] (fp16) = sum_e x[b][t][e] * E'[e][j];  one block per t.
__global__ __launch_bounds__(512, 1) void vgemm_kernel(
    const float* __restrict__ x, const _Float16* __restrict__ Bt,
    _Float16* __restrict__ v)
{
  const int t = blockIdx.x;
  const int tid = threadIdx.x, l = tid & 63, w = tid >> 6;
  __shared__ __align__(16) _Float16 A[ATILE_HALVES];
  {
    const int row = tid >> 3, part = tid & 7;
    const float4* sp = (const float4*)(x + ((size_t)row * TT + t) * DH);
#pragma unroll
    for (int i = 0; i < 8; ++i) {
      const int ks = i * 8 + part;
      const float4 a = sp[ks * 2], b = sp[ks * 2 + 1];
      f16x8 vv;
      vv[0] = (_Float16)a.x; vv[1] = (_Float16)a.y; vv[2] = (_Float16)a.z; vv[3] = (_Float16)a.w;
      vv[4] = (_Float16)b.x; vv[5] = (_Float16)b.y; vv[6] = (_Float16)b.z; vv[7] = (_Float16)b.w;
      *(f16x8*)(A + ((size_t)ks * 65 + row) * 8) = vv;
    }
  }
  __syncthreads();
  const int jb = w * 64;
  const int arowb = l & 15, g = l >> 4;
  f32x4 acc[4][4];
#pragma unroll
  for (int mf = 0; mf < 4; ++mf)
#pragma unroll
    for (int nf = 0; nf < 4; ++nf)
#pragma unroll
      for (int e = 0; e < 4; ++e) acc[mf][nf][e] = 0.f;
#pragma unroll
  for (int kk = 0; kk < 16; ++kk) {
    const int ks = kk * 4 + g;
    f16x8 am[4], bn[4];
#pragma unroll
    for (int mf = 0; mf < 4; ++mf)
      am[mf] = *(const f16x8*)(A + ((size_t)ks * 65 + mf * 16 + arowb) * 8);
#pragma unroll
    for (int nf = 0; nf < 4; ++nf)
      bn[nf] = *(const f16x8*)(Bt + (size_t)(jb + nf * 16 + arowb) * DH + kk * 32 + g * 8);
#pragma unroll
    for (int mf = 0; mf < 4; ++mf)
#pragma unroll
      for (int nf = 0; nf < 4; ++nf)
        acc[mf][nf] = __builtin_amdgcn_mfma_f32_16x16x32_f16(am[mf], bn[nf], acc[mf][nf], 0, 0, 0);
  }
#pragma unroll
  for (int mf = 0; mf < 4; ++mf)
#pragma unroll
    for (int nf = 0; nf < 4; ++nf)
#pragma unroll
      for (int i = 0; i < 4; ++i) {
        const int r = mf * 16 + (l >> 4) * 4 + i;
        const int j = jb + nf * 16 + (l & 15);
        v[((size_t)t * BB + r) * DH + j] = (_Float16)acc[mf][nf][i];
      }
}

// ---------------------------------------------------------------- main RNN

// Stage [64x512] fp16 -> LDS. COH: volatile (L2-bypass) loads; else normal.
template <bool COH>
__device__ __forceinline__ void stage_h(_Float16* __restrict__ A,
                                        const _Float16* __restrict__ src,
                                        float* muA, float* rsA, bool stats,
                                        int tid)
{
  const int row = tid >> 3, part = tid & 7;
  const _Float16* sp = src + (size_t)row * DH;
  f16x8 v[8];
#pragma unroll
  for (int i = 0; i < 8; ++i) {
    if (COH) v[i] = cload(sp + (size_t)(i * 8 + part) * 8);
    else     v[i] = *(const f16x8*)(sp + (size_t)(i * 8 + part) * 8);
  }
  float sum = 0.f, sq = 0.f;
#pragma unroll
  for (int i = 0; i < 8; ++i) {
    const int ks = i * 8 + part;
    *(f16x8*)(A + ((size_t)ks * 65 + row) * 8) = v[i];
    if (stats) {
#pragma unroll
      for (int e = 0; e < 8; ++e) { const float f = (float)v[i][e]; sum += f; sq += f * f; }
    }
  }
  if (stats) {
    sum += __shfl_xor(sum, 1); sq += __shfl_xor(sq, 1);
    sum += __shfl_xor(sum, 2); sq += __shfl_xor(sq, 2);
    sum += __shfl_xor(sum, 4); sq += __shfl_xor(sq, 4);
    if (part == 0) {
      const float mu = sum * (1.f / DH);
      const float var = sq * (1.f / DH) - mu * mu;
      muA[row] = mu; rsA[row] = rsqrtf(var + 1e-5f);
    }
  }
}

__device__ __forceinline__ void stage_x(_Float16* __restrict__ A,
                                        const float* __restrict__ inputs,
                                        int t, int tid)
{
  const int row = tid >> 3, part = tid & 7;
  const float4* sp = (const float4*)(inputs + ((size_t)row * TT + t) * DH);
#pragma unroll
  for (int i = 0; i < 8; ++i) {
    const int ks = i * 8 + part;
    const float4 a = sp[ks * 2], b = sp[ks * 2 + 1];
    f16x8 vv;
    vv[0] = (_Float16)a.x; vv[1] = (_Float16)a.y; vv[2] = (_Float16)a.z; vv[3] = (_Float16)a.w;
    vv[4] = (_Float16)b.x; vv[5] = (_Float16)b.y; vv[6] = (_Float16)b.z; vv[7] = (_Float16)b.w;
    *(f16x8*)(A + ((size_t)ks * 65 + row) * 8) = vv;
  }
}

__device__ __forceinline__ void spin_mask(unsigned* p, unsigned tgt) {
  while (true) {
    bool mine = true;
    if (p) mine = (__hip_atomic_load(p, __ATOMIC_RELAXED, __HIP_MEMORY_SCOPE_AGENT) >= tgt);
    if (__all(mine)) break;
    __builtin_amdgcn_s_sleep(2);
  }
}

// 24 blocks: stage s = bid>>3 (layer), slice c = bid&7 (64 output cols).
// UNIQ=1: unique h buffer per (s,t) -> normal cached consumer loads, no fences,
//         no back-pressure. UNIQ=0: RD-deep ring + volatile loads (fallback).
template <int UNIQ>
__global__ __launch_bounds__(512, 1) void rnn8_kernel(
    const float* __restrict__ inputs, const _Float16* __restrict__ v_all,
    const int use_v, const _Float16* __restrict__ packB,
    const float* __restrict__ bfold, const float* __restrict__ csum,
    _Float16* __restrict__ h_base, unsigned* __restrict__ arr,
    unsigned* __restrict__ cons)
{
  const int bid = blockIdx.x;
  const int s = bid >> 3, c = bid & 7;
  const int tid = threadIdx.x;
  const int l = tid & 63, w = tid >> 6;
  const int mg = w >> 2, ng = w & 3;     // 2 x 4 wave grid

  __shared__ __align__(16) _Float16 A1[ATILE_HALVES];
  __shared__ __align__(16) _Float16 A2[ATILE_HALVES];
  __shared__ __align__(16) _Float16 hout[64][72];
  __shared__ float muS[64], rsS[64];

  const bool sx = (s == 0);
  const bool havev = (use_v != 0);
  const bool needX = (!sx || !havev);

  // ---- one-time register-resident B slices (16 col set per wave)
  const int colbase = c * 64 + ng * 16 + (l & 15);
  const int kbase = (l >> 4) * 8;
  f16x8 Bx[16], Bh[16];
  {
    const _Float16* ph = packB + ((size_t)(s * 2 + 1) * DH + colbase) * DH + kbase;
#pragma unroll
    for (int kk = 0; kk < 16; ++kk) Bh[kk] = *(const f16x8*)(ph + kk * 32);
  }
  if (needX) {
    const _Float16* px = packB + ((size_t)(s * 2 + 0) * DH + colbase) * DH + kbase;
#pragma unroll
    for (int kk = 0; kk < 16; ++kk) Bx[kk] = *(const f16x8*)(px + kk * 32);
  }

  const float b_j = bfold[s * DH + colbase];
  const float cs_j = (s > 0) ? csum[(s - 1) * DH + colbase] : 0.f;
  const int g = l >> 4;

  for (int t = 0; t < TT; ++t) {
    // ---------- phase 1: own-layer recurrent operand (A2) ----------
    if (w == 0) {
      unsigned* p = nullptr; unsigned tgt = 0;
      if (l < 8) {
        if (t >= 1) { p = arr + (s * 8 + l) * 16; tgt = (unsigned)t; }
      } else if (!UNIQ && l >= 16 && l < 24 && s < 2 && t >= RD) {
        p = cons + (s * 8 + (l - 16)) * 16; tgt = (unsigned)(t - RD + 1);
      }
      spin_mask(p, tgt);
    }
    __syncthreads();
    if (t >= 1) {
      const _Float16* hsrc = UNIQ
        ? h_base + ((size_t)s * TT + (t - 1)) * BB * DH
        : h_base + (size_t)(s * RD + ((t - 1) & (RD - 1))) * BB * DH;
      stage_h<(UNIQ == 0)>(A2, hsrc, nullptr, nullptr, false, tid);
    }
    __syncthreads();

    f32x4 accX[2], accH[2];
#pragma unroll
    for (int mf = 0; mf < 2; ++mf)
#pragma unroll
      for (int e = 0; e < 4; ++e) { accX[mf][e] = 0.f; accH[mf][e] = 0.f; }

    // accH now — overlaps with the upstream stage still producing h_{s-1}(t)
    if (t >= 1) {
#pragma unroll
      for (int kk = 0; kk < 16; ++kk) {
        const int ks = kk * 4 + g;
#pragma unroll
        for (int mf = 0; mf < 2; ++mf) {
          const int arow = mg * 32 + mf * 16 + (l & 15);
          const f16x8 aH = *(const f16x8*)(A2 + ((size_t)ks * 65 + arow) * 8);
          accH[mf] = __builtin_amdgcn_mfma_f32_16x16x32_f16(aH, Bh[kk], accH[mf], 0, 0, 0);
        }
      }
    }

    // ---------- phase 2: upstream operand (A1) ----------
    if (s > 0) {
      if (w == 0) {
        unsigned* p = (l < 8) ? (arr + ((s - 1) * 8 + l) * 16) : nullptr;
        spin_mask(p, (unsigned)(t + 1));
      }
      __syncthreads();
      const _Float16* hsrc = UNIQ
        ? h_base + ((size_t)(s - 1) * TT + t) * BB * DH
        : h_base + (size_t)((s - 1) * RD + (t & (RD - 1))) * BB * DH;
      stage_h<(UNIQ == 0)>(A1, hsrc, muS, rsS, true, tid);
      __syncthreads();
      if (!UNIQ && tid == 0)
        __hip_atomic_store(cons + ((s - 1) * 8 + c) * 16, (unsigned)(t + 1),
                           __ATOMIC_RELAXED, __HIP_MEMORY_SCOPE_AGENT);
    } else if (!havev) {
      stage_x(A1, inputs, t, tid);
      __syncthreads();
    }

    if (needX) {
#pragma unroll
      for (int kk = 0; kk < 16; ++kk) {
        const int ks = kk * 4 + g;
#pragma unroll
        for (int mf = 0; mf < 2; ++mf) {
          const int arow = mg * 32 + mf * 16 + (l & 15);
          const f16x8 aX = *(const f16x8*)(A1 + ((size_t)ks * 65 + arow) * 8);
          accX[mf] = __builtin_amdgcn_mfma_f32_16x16x32_f16(aX, Bx[kk], accX[mf], 0, 0, 0);
        }
      }
    }

    // ---------- epilogue -> hout (LDS), then coalesced coherent writeback
    const int jl = ng * 16 + (l & 15);
#pragma unroll
    for (int mf = 0; mf < 2; ++mf)
#pragma unroll
      for (int i = 0; i < 4; ++i) {
        const int r = mg * 32 + mf * 16 + (l >> 4) * 4 + i;
        float p;
        if (sx) {
          float v0;
          if (havev) v0 = (float)v_all[((size_t)t * BB + r) * DH + c * 64 + jl];
          else       v0 = accX[mf][i];
          p = v0 + accH[mf][i] + b_j;
        } else {
          p = rsS[r] * (accX[mf][i] - muS[r] * cs_j) + accH[mf][i] + b_j;
        }
        hout[r][jl] = (_Float16)tanhf(p);
      }
    __syncthreads();
    {
      _Float16* dst = UNIQ
        ? h_base + ((size_t)s * TT + t) * BB * DH
        : h_base + (size_t)(s * RD + (t & (RD - 1))) * BB * DH;
      const int row = tid >> 3, ch = tid & 7;
      const f16x8 hv = *(const f16x8*)(&hout[row][ch * 8]);
      cstore(dst + (size_t)row * DH + c * 64 + ch * 8, hv);
    }
    __syncthreads();   // drains vmcnt: write-through stores visible at LLC
    if (tid == 0)
      __hip_atomic_store(arr + (s * 8 + c) * 16, (unsigned)(t + 1),
                         __ATOMIC_RELAXED, __HIP_MEMORY_SCOPE_AGENT);
  }
}

// ---------------------------------------------------------------- classifier

__global__ __launch_bounds__(64) void clf_kernel(
    const _Float16* __restrict__ h2, const float* __restrict__ clfwf,
    const float* __restrict__ clfbf, float* __restrict__ out)
{
  const int b = blockIdx.x, d = threadIdx.x;
  __shared__ float o2[DH];
  const _Float16* hrow = h2 + (size_t)b * DH;
  float sum = 0.f, sq = 0.f;
#pragma unroll
  for (int i = 0; i < 8; ++i) {
    const float v = (float)hrow[d * 8 + i];
    sum += v; sq += v * v;
  }
#pragma unroll
  for (int off = 32; off; off >>= 1) { sum += __shfl_xor(sum, off); sq += __shfl_xor(sq, off); }
  const float mu = sum * (1.f / DH);
  const float rs = rsqrtf(sq * (1.f / DH) - mu * mu + 1e-5f);
#pragma unroll
  for (int i = 0; i < 8; ++i) o2[d * 8 + i] = ((float)hrow[d * 8 + i] - mu) * rs;
  __syncthreads();
  float acc = clfbf[d];
#pragma unroll 8
  for (int k = 0; k < DH; ++k) acc = fmaf(o2[k], clfwf[k * DT + d], acc);
  float mx = acc;
#pragma unroll
  for (int off = 32; off; off >>= 1) mx = fmaxf(mx, __shfl_xor(mx, off));
  const float e = expf(acc - mx);
  float ss = e;
#pragma unroll
  for (int off = 32; off; off >>= 1) ss += __shfl_xor(ss, off);
  out[(size_t)b * DT + d] = e / ss;
}

// ---------------------------------------------------------------- launch

extern "C" void kernel_launch(void* const* d_in, const int* in_sizes, int n_in,
                              void* d_out, int out_size, void* d_ws, size_t ws_size,
                              hipStream_t stream) {
  const float* inputs = (const float*)d_in[0];
  const float* emb    = (const float*)d_in[1];
  const float* wx0    = (const float*)d_in[2];
  const float* wh0    = (const float*)d_in[3];
  const float* b0     = (const float*)d_in[4];
  const float* wx1    = (const float*)d_in[5];
  const float* wh1    = (const float*)d_in[6];
  const float* b1     = (const float*)d_in[7];
  const float* wx2    = (const float*)d_in[8];
  const float* wh2    = (const float*)d_in[9];
  const float* b2     = (const float*)d_in[10];
  const float* gamma  = (const float*)d_in[11];
  const float* beta   = (const float*)d_in[12];
  const float* clfw   = (const float*)d_in[13];
  const float* clfb   = (const float*)d_in[14];
  float* out = (float*)d_out;

  char* ws = (char*)d_ws;
  size_t off = 0;
  float*    Ep    = (float*)(ws + off);    off += (size_t)DH * DH * 4;               // 1 MB
  _Float16* packB = (_Float16*)(ws + off); off += (size_t)6 * DH * DH * 2;           // 3 MB
  float*    bfold = (float*)(ws + off);    off += (size_t)3 * DH * 4;
  float*    csumP = (float*)(ws + off);    off += (size_t)2 * DH * 4;
  float*    clfwf = (float*)(ws + off);    off += (size_t)DH * DT * 4;               // 128 KB
  float*    clfbf = (float*)(ws + off);    off += 256;
  unsigned* arr   = (unsigned*)(ws + off); off += (size_t)3 * 8 * 16 * 4;            // 1.5 KB
  unsigned* cons  = (unsigned*)(ws + off); off += (size_t)2 * 8 * 16 * 4;            // 1 KB
  off = (off + 255) & ~(size_t)255;
  _Float16* h_base = (_Float16*)(ws + off);

  const size_t uniq_h_bytes = (size_t)3 * TT * BB * DH * 2;                          // 192 MB
  const size_t ring_h_bytes = (size_t)3 * RD * BB * DH * 2;                          // 768 KB
  const size_t v_bytes = (size_t)TT * BB * DH * 2;                                   // 64 MB

  const int uniq = (ws_size >= off + uniq_h_bytes) ? 1 : 0;
  const size_t h_bytes = uniq ? uniq_h_bytes : ring_h_bytes;
  size_t off_v = ((off + h_bytes + 255) & ~(size_t)255);
  _Float16* v_all = (_Float16*)(ws + off_v);
  const int use_v = (ws_size >= off_v + v_bytes) ? 1 : 0;

  (void)hipMemsetAsync(arr, 0, (size_t)(3 * 8 * 16 + 2 * 8 * 16) * 4, stream);
  hipLaunchKernelGGL(eprime_kernel, dim3(DH), dim3(512), 0, stream, emb, wx0, Ep);
  hipLaunchKernelGGL(pack_kernel, dim3(8, 8, 6), dim3(512), 0, stream,
                     Ep, wh0, wx1, wh1, wx2, wh2, gamma, packB);
  hipLaunchKernelGGL(fold_kernel, dim3(2), dim3(512), 0, stream,
                     b0, b1, b2, wx1, wx2, gamma, beta, clfw, clfb,
                     bfold, csumP, clfwf, clfbf);
  if (use_v)
    hipLaunchKernelGGL(vgemm_kernel, dim3(TT), dim3(512), 0, stream,
                       inputs, packB, v_all);

  if (uniq)
    hipLaunchKernelGGL((rnn8_kernel<1>), dim3(24), dim3(512), 0, stream,
                       inputs, v_all, use_v, packB, bfold, csumP, h_base, arr, cons);
  else
    hipLaunchKernelGGL((rnn8_kernel<0>), dim3(24), dim3(512), 0, stream,
                       inputs, v_all, use_v, packB, bfold, csumP, h_base, arr, cons);

  const _Float16* h2fin = uniq
    ? h_base + ((size_t)2 * TT + (TT - 1)) * BB * DH
    : h_base + (size_t)(2 * RD + ((TT - 1) & (RD - 1))) * BB * DH;
  hipLaunchKernelGGL(clf_kernel, dim3(BB), dim3(DT), 0, stream,
                     h2fin, clfwf, clfbf, out);
}